// Round 6
// baseline (834.766 us; speedup 1.0000x reference)
//
#include <hip/hip_runtime.h>
#include <hip/hip_bf16.h>
#include <hip/hip_fp16.h>
#include <math.h>

// Channel-major ([b][hw][c]) MFMA bf16 pipeline, fp32 accumulate.
// - g-branch: numerator sum(g^2) via bf16 MFMA; denominator analytic (sum_hw sn == 0).
// - conv3x3: weights fragment-major, direct global->VGPR; patch LDS double-buffered.
// - All MFMA GEMMs double-buffer LDS (1 barrier/K-step).
// - Attention: logits stored fp16; softmax fused into PV staging (rowstat + softpv).
// - NO XCD swizzle: workspace is L3-resident; default dispatch preserves
//   producer->consumer block->XCD affinity (round-5 A/B: swizzle cost ~7%).

typedef __attribute__((ext_vector_type(8))) short short8;
typedef __attribute__((ext_vector_type(4))) float f32x4;
typedef unsigned short us;
#define MFMA16 __builtin_amdgcn_mfma_f32_16x16x32_bf16

struct h16 { us v; };  // fp16 storage tag for GEMM output

template <class A, class B> struct SameT { static constexpr bool v = false; };
template <class A> struct SameT<A, A> { static constexpr bool v = true; };

__device__ inline float b2f(us b) { return __uint_as_float(((unsigned)b) << 16); }
__device__ inline us f2b(float f) {
    unsigned u = __float_as_uint(f);
    return (us)((u + 0x7FFFu + ((u >> 16) & 1u)) >> 16);
}

__device__ inline double blockReduceSumD(double v, double* sh) {
    int t = threadIdx.x;
    sh[t] = v; __syncthreads();
    for (int s = blockDim.x >> 1; s > 0; s >>= 1) {
        if (t < s) sh[t] += sh[t + s];
        __syncthreads();
    }
    double r = sh[0]; __syncthreads();
    return r;
}

// ---------- per-(b,c) spatial stats ----------
__global__ __launch_bounds__(256) void stats_k(const float* __restrict__ X,
                                               float* __restrict__ mean,
                                               float* __restrict__ inv, int HW) {
    __shared__ double sh[256];
    int bc = blockIdx.x;
    const float* x = X + (size_t)bc * HW;
    int t = threadIdx.x;
    float v[4];
    double s = 0.0;
    #pragma unroll
    for (int r = 0; r < 4; ++r) { v[r] = x[t + r * 256]; s += (double)v[r]; }
    double tot = blockReduceSumD(s, sh);
    double ss = 0.0;
    #pragma unroll
    for (int r = 0; r < 4; ++r) ss += (double)v[r] * (double)v[r];
    double tot2 = blockReduceSumD(ss, sh);
    if (t == 0) {
        double m = tot / HW;
        double var = (tot2 - tot * tot / HW) / (HW - 1);
        mean[bc] = (float)m;
        inv[bc] = (float)(1.0 / sqrt(var + 1e-5));
    }
}

// ---------- transpose [b][C][HW] fp32 -> up to 3 bf16 [b][HW][C] outputs ----------
__global__ __launch_bounds__(256) void trn_k(const float* __restrict__ X,
                                             const float* __restrict__ mean,
                                             const float* __restrict__ inv,
                                             us* __restrict__ Yn, us* __restrict__ Yc,
                                             us* __restrict__ Yr, int C, int HW) {
    __shared__ us Ln[64 * 65];
    __shared__ us Lc[64 * 65];
    __shared__ us Lr[64 * 65];
    int bz = blockIdx.z, c0 = blockIdx.y * 64, h0 = blockIdx.x * 64;
    const float* Xb = X + (size_t)bz * C * HW;
    int t = threadIdx.x;
    int cl = t >> 3, h8 = (t & 7) * 8;
    #pragma unroll
    for (int half = 0; half < 2; ++half) {
        int c = cl + half * 32;
        int gc = c0 + c;
        float m = mean[bz * C + gc], iv = inv[bz * C + gc];
        const float4* s4 = (const float4*)&Xb[(size_t)gc * HW + h0 + h8];
        float4 f0 = s4[0], f1 = s4[1];
        float vv[8] = {f0.x, f0.y, f0.z, f0.w, f1.x, f1.y, f1.z, f1.w};
        #pragma unroll
        for (int i = 0; i < 8; ++i) {
            int li = c * 65 + h8 + i;
            if (Yn) Ln[li] = f2b((vv[i] - m) * iv);
            if (Yc) Lc[li] = f2b(vv[i] - m);
            if (Yr) Lr[li] = f2b(vv[i]);
        }
    }
    __syncthreads();
    int hl = t >> 3, c8 = (t & 7) * 8;
    #pragma unroll
    for (int half = 0; half < 2; ++half) {
        int hh = hl + half * 32;
        size_t off = ((size_t)bz * HW + h0 + hh) * (size_t)C + c0 + c8;
        us tmp[8];
        if (Yn) {
            #pragma unroll
            for (int i = 0; i < 8; ++i) tmp[i] = Ln[(c8 + i) * 65 + hh];
            *(uint4*)&Yn[off] = *(const uint4*)tmp;
        }
        if (Yc) {
            #pragma unroll
            for (int i = 0; i < 8; ++i) tmp[i] = Lc[(c8 + i) * 65 + hh];
            *(uint4*)&Yc[off] = *(const uint4*)tmp;
        }
        if (Yr) {
            #pragma unroll
            for (int i = 0; i < 8; ++i) tmp[i] = Lr[(c8 + i) * 65 + hh];
            *(uint4*)&Yr[off] = *(const uint4*)tmp;
        }
    }
}

// ---------- staging: 16 k-contiguous elems -> bf16 LDS ----------
template <typename TE>
__device__ inline void stage16(const TE* __restrict__ src, bool valid, us* dst) {
    us tmp[16];
    if (valid) {
        if constexpr (sizeof(TE) == 2) {
            uint4 a = ((const uint4*)src)[0], b = ((const uint4*)src)[1];
            *(uint4*)&tmp[0] = a; *(uint4*)&tmp[8] = b;
        } else {
            const float4* s4 = (const float4*)src;
            float4 f0 = s4[0], f1 = s4[1], f2 = s4[2], f3 = s4[3];
            float vv[16] = {f0.x, f0.y, f0.z, f0.w, f1.x, f1.y, f1.z, f1.w,
                            f2.x, f2.y, f2.z, f2.w, f3.x, f3.y, f3.z, f3.w};
            #pragma unroll
            for (int i = 0; i < 16; ++i) tmp[i] = f2b(vv[i]);
        }
    } else {
        #pragma unroll
        for (int i = 0; i < 16; ++i) tmp[i] = 0;
    }
    ((uint4*)dst)[0] = *(uint4*)&tmp[0];
    ((uint4*)dst)[1] = *(uint4*)&tmp[8];
}

// ---------- 128x128 MFMA GEMM, double-buffered LDS ----------
// acc[m][n] = sum_k A[m][k] * B[n][k]
// OUTT=0: Y[b][m][n] row-major (+add_src fp32); OUTT=1: Y[b][n][m]
template <typename TAel, typename TBel, typename TOUT, int OUTT>
__global__ __launch_bounds__(256) void mf2_k(const TAel* __restrict__ A, long astride, int lda,
                                             const TBel* __restrict__ B, long bstride, int ldb,
                                             const float* __restrict__ bias,
                                             TOUT* __restrict__ Y,
                                             const float* __restrict__ add_src,
                                             int K, int M, int N, int relu) {
    __shared__ us As[2][128][40];
    __shared__ us Bs[2][128][40];
    int bz = blockIdx.z;
    int mbase = blockIdx.y * 128, nbase = blockIdx.x * 128;
    const TAel* Ab = A + (size_t)bz * astride;
    const TBel* Bb = B + (size_t)bz * bstride;
    int t = threadIdx.x;
    int row = t & 127, kh = t >> 7;
    int wave = t >> 6, lane = t & 63, lm = lane & 15, q = lane >> 4;
    int mh = (wave >> 1) * 64, nh = (wave & 1) * 64;
    int gm = mbase + row, gn = nbase + row;
    bool vm = gm < M, vn = gn < N;

    auto stage = [&](int buf, int kb) {
        stage16(Ab + (size_t)gm * lda + kb + kh * 16, vm, &As[buf][row][kh * 16]);
        stage16(Bb + (size_t)gn * ldb + kb + kh * 16, vn, &Bs[buf][row][kh * 16]);
    };

    f32x4 acc[4][4];
    #pragma unroll
    for (int i = 0; i < 4; ++i)
        #pragma unroll
        for (int j = 0; j < 4; ++j) acc[i][j] = (f32x4){0.f, 0.f, 0.f, 0.f};

    stage(0, 0);
    __syncthreads();
    int cur = 0;
    for (int kb = 0; kb < K; kb += 32) {
        if (kb + 32 < K) stage(cur ^ 1, kb + 32);
        short8 af[4], bf[4];
        #pragma unroll
        for (int i = 0; i < 4; ++i) af[i] = *(const short8*)&As[cur][mh + i * 16 + lm][q * 8];
        #pragma unroll
        for (int j = 0; j < 4; ++j) bf[j] = *(const short8*)&Bs[cur][nh + j * 16 + lm][q * 8];
        #pragma unroll
        for (int i = 0; i < 4; ++i)
            #pragma unroll
            for (int j = 0; j < 4; ++j)
                acc[i][j] = MFMA16(af[i], bf[j], acc[i][j], 0, 0, 0);
        __syncthreads();
        cur ^= 1;
    }

    #pragma unroll
    for (int i = 0; i < 4; ++i) {
        int m0 = mbase + mh + i * 16 + q * 4;
        if (m0 >= M) continue;
        float bv[4];
        #pragma unroll
        for (int r = 0; r < 4; ++r) bv[r] = bias ? bias[m0 + r] : 0.f;
        #pragma unroll
        for (int j = 0; j < 4; ++j) {
            int n = nbase + nh + j * 16 + lm;
            if (n >= N) continue;
            float v[4];
            #pragma unroll
            for (int r = 0; r < 4; ++r) {
                float x = acc[i][j][r] + bv[r];
                if (relu) x = (x > 0.f) ? x : 0.f;
                v[r] = x;
            }
            if (OUTT == 1) {
                size_t off = ((size_t)bz * N + n) * (size_t)M + m0;
                if constexpr (sizeof(TOUT) == 2) {
                    us o4[4];
                    #pragma unroll
                    for (int r = 0; r < 4; ++r) o4[r] = f2b(v[r]);
                    *(uint2*)&Y[off] = *(const uint2*)o4;
                } else {
                    float4 f4 = make_float4(v[0], v[1], v[2], v[3]);
                    *(float4*)&Y[off] = f4;
                }
            } else {
                #pragma unroll
                for (int r = 0; r < 4; ++r) {
                    size_t off = ((size_t)bz * M + m0 + r) * (size_t)N + n;
                    float x = v[r];
                    if (add_src) x += add_src[off];
                    if constexpr (SameT<TOUT, us>::v) Y[off] = f2b(x);
                    else if constexpr (SameT<TOUT, h16>::v) {
                        h16 hh; hh.v = __half_as_ushort(__float2half(x)); Y[off] = hh;
                    } else Y[off] = x;
                }
            }
        }
    }
}

// ---------- stacked-M MFMA GEMM (dbuf): A bf16 [Mstack][K], out [b][n][Mstack] ----------
struct SBias {
    const float* bp[10];
    int moff[10];
    unsigned relu;
};
__global__ __launch_bounds__(256) void mfs_k(const us* __restrict__ A,
                                             const us* __restrict__ B, long bstride, int ldb,
                                             us* __restrict__ Y, int ldy,
                                             SBias sb, int K, int N) {
    __shared__ us As[2][128][40];
    __shared__ us Bs[2][128][40];
    int bz = blockIdx.z;
    int mbase = blockIdx.y * 128, nbase = blockIdx.x * 128;
    const us* Bb = B + (size_t)bz * bstride;
    int t = threadIdx.x;
    int row = t & 127, kh = t >> 7;
    int wave = t >> 6, lane = t & 63, lm = lane & 15, q = lane >> 4;
    int mh = (wave >> 1) * 64, nh = (wave & 1) * 64;
    int relu = (sb.relu >> blockIdx.y) & 1;
    const float* bias = sb.bp[blockIdx.y];
    int moff = sb.moff[blockIdx.y];

    auto stage = [&](int buf, int kb) {
        stage16(A + (size_t)(mbase + row) * K + kb + kh * 16, true, &As[buf][row][kh * 16]);
        stage16(Bb + (size_t)(nbase + row) * ldb + kb + kh * 16, true, &Bs[buf][row][kh * 16]);
    };

    f32x4 acc[4][4];
    #pragma unroll
    for (int i = 0; i < 4; ++i)
        #pragma unroll
        for (int j = 0; j < 4; ++j) acc[i][j] = (f32x4){0.f, 0.f, 0.f, 0.f};

    stage(0, 0);
    __syncthreads();
    int cur = 0;
    for (int kb = 0; kb < K; kb += 32) {
        if (kb + 32 < K) stage(cur ^ 1, kb + 32);
        short8 af[4], bf[4];
        #pragma unroll
        for (int i = 0; i < 4; ++i) af[i] = *(const short8*)&As[cur][mh + i * 16 + lm][q * 8];
        #pragma unroll
        for (int j = 0; j < 4; ++j) bf[j] = *(const short8*)&Bs[cur][nh + j * 16 + lm][q * 8];
        #pragma unroll
        for (int i = 0; i < 4; ++i)
            #pragma unroll
            for (int j = 0; j < 4; ++j)
                acc[i][j] = MFMA16(af[i], bf[j], acc[i][j], 0, 0, 0);
        __syncthreads();
        cur ^= 1;
    }

    #pragma unroll
    for (int i = 0; i < 4; ++i) {
        int m0 = mbase + mh + i * 16 + q * 4;
        float bv[4];
        #pragma unroll
        for (int r = 0; r < 4; ++r) bv[r] = bias[m0 - moff + r];
        #pragma unroll
        for (int j = 0; j < 4; ++j) {
            int n = nbase + nh + j * 16 + lm;
            us o4[4];
            #pragma unroll
            for (int r = 0; r < 4; ++r) {
                float x = acc[i][j][r] + bv[r];
                if (relu) x = (x > 0.f) ? x : 0.f;
                o4[r] = f2b(x);
            }
            *(uint2*)&Y[((size_t)bz * N + n) * ldy + m0] = *(const uint2*)o4;
        }
    }
}

// ---------- row stats for fp16 logits: m[row], 1/sum(exp(s-m)) ----------
__global__ __launch_bounds__(256) void rowstat_k(const us* __restrict__ S,
                                                 float* __restrict__ mrow,
                                                 float* __restrict__ ilrow) {
    size_t row = (size_t)blockIdx.x * 4 + (threadIdx.x >> 6);
    int lane = threadIdx.x & 63;
    const us* r = S + row * 1024 + lane * 16;
    us raw[16];
    *(uint4*)&raw[0] = ((const uint4*)r)[0];
    *(uint4*)&raw[8] = ((const uint4*)r)[1];
    float v[16];
    float m = -INFINITY;
    #pragma unroll
    for (int e = 0; e < 16; ++e) {
        v[e] = __half2float(__ushort_as_half(raw[e]));
        m = fmaxf(m, v[e]);
    }
    #pragma unroll
    for (int off = 32; off > 0; off >>= 1) m = fmaxf(m, __shfl_xor(m, off));
    float l = 0.f;
    #pragma unroll
    for (int e = 0; e < 16; ++e) l += expf(v[e] - m);
    #pragma unroll
    for (int off = 32; off > 0; off >>= 1) l += __shfl_xor(l, off);
    if (lane == 0) { mrow[row] = m; ilrow[row] = 1.f / l; }
}

// ---------- fused softmax+PV: part3[b][i][c] = sum_j exp(S[i][j]-m)*il * H[c][j] ----------
__global__ __launch_bounds__(256) void softpv_k(const us* __restrict__ S,
                                                const float* __restrict__ mrow,
                                                const float* __restrict__ ilrow,
                                                const us* __restrict__ H,
                                                us* __restrict__ Y) {
    __shared__ us As[2][128][40];
    __shared__ us Bs[2][128][40];
    const int Kd = 1024, M = 1024, N = 512;
    int bz = blockIdx.z;
    int mbase = blockIdx.y * 128, nbase = blockIdx.x * 128;
    const us* Sb = S + (size_t)bz * M * Kd;
    const us* Hb = H + (size_t)bz * N * Kd;
    int t = threadIdx.x;
    int row = t & 127, kh = t >> 7;
    int wave = t >> 6, lane = t & 63, lm = lane & 15, q = lane >> 4;
    int mh = (wave >> 1) * 64, nh = (wave & 1) * 64;
    float mr = mrow[(size_t)bz * M + mbase + row];
    float ilr = ilrow[(size_t)bz * M + mbase + row];

    auto stageA = [&](int buf, int kb) {
        const us* src = Sb + (size_t)(mbase + row) * Kd + kb + kh * 16;
        us raw[16];
        *(uint4*)&raw[0] = ((const uint4*)src)[0];
        *(uint4*)&raw[8] = ((const uint4*)src)[1];
        us out[16];
        #pragma unroll
        for (int e = 0; e < 16; ++e) {
            float v = __half2float(__ushort_as_half(raw[e]));
            out[e] = f2b(expf(v - mr) * ilr);
        }
        us* dst = &As[buf][row][kh * 16];
        ((uint4*)dst)[0] = *(uint4*)&out[0];
        ((uint4*)dst)[1] = *(uint4*)&out[8];
    };
    auto stageB = [&](int buf, int kb) {
        stage16(Hb + (size_t)(nbase + row) * Kd + kb + kh * 16, true, &Bs[buf][row][kh * 16]);
    };

    f32x4 acc[4][4];
    #pragma unroll
    for (int i = 0; i < 4; ++i)
        #pragma unroll
        for (int j = 0; j < 4; ++j) acc[i][j] = (f32x4){0.f, 0.f, 0.f, 0.f};

    stageA(0, 0); stageB(0, 0);
    __syncthreads();
    int cur = 0;
    for (int kb = 0; kb < Kd; kb += 32) {
        if (kb + 32 < Kd) { stageA(cur ^ 1, kb + 32); stageB(cur ^ 1, kb + 32); }
        short8 af[4], bf[4];
        #pragma unroll
        for (int i = 0; i < 4; ++i) af[i] = *(const short8*)&As[cur][mh + i * 16 + lm][q * 8];
        #pragma unroll
        for (int j = 0; j < 4; ++j) bf[j] = *(const short8*)&Bs[cur][nh + j * 16 + lm][q * 8];
        #pragma unroll
        for (int i = 0; i < 4; ++i)
            #pragma unroll
            for (int j = 0; j < 4; ++j)
                acc[i][j] = MFMA16(af[i], bf[j], acc[i][j], 0, 0, 0);
        __syncthreads();
        cur ^= 1;
    }

    #pragma unroll
    for (int i = 0; i < 4; ++i) {
        int m0 = mbase + mh + i * 16 + q * 4;
        #pragma unroll
        for (int j = 0; j < 4; ++j) {
            int n = nbase + nh + j * 16 + lm;
            #pragma unroll
            for (int r = 0; r < 4; ++r) {
                size_t off = ((size_t)bz * M + m0 + r) * (size_t)N + n;
                Y[off] = f2b(acc[i][j][r]);
            }
        }
    }
}

// ---------- weight concat/convert fp32 -> bf16 arena ----------
struct CpyArg {
    const float* src[11];
    unsigned long long dstoff[11];
    int len[11];
};
__global__ __launch_bounds__(256) void wcat_k(CpyArg a, us* __restrict__ arena) {
    int seg = blockIdx.y;
    int idx = blockIdx.x * 256 + threadIdx.x;
    if (idx < a.len[seg]) arena[a.dstoff[seg] + idx] = f2b(a.src[seg][idx]);
}

// ---------- conv3x3 weight reorder: fragment-major ----------
__global__ __launch_bounds__(256) void reorder_wf_k(const float* __restrict__ W,
                                                    us* __restrict__ Wf, int O, int Cin) {
    int idx = blockIdx.x * 256 + threadIdx.x;
    int OT = O >> 6, KB = Cin >> 5;
    int total = OT * KB * 9 * 4 * 64;
    if (idx >= total) return;
    int lane = idx & 63;
    int f = idx >> 6;
    int i = f & 1, half = (f >> 1) & 1;
    int tf = f >> 2;
    int tap = tf % 9;
    int rest = tf / 9;
    int kb = rest % KB, ot = rest / KB;
    int o = ot * 64 + half * 32 + i * 16 + (lane & 15);
    int cb = kb * 32 + (lane >> 4) * 8;
    us v[8];
    #pragma unroll
    for (int e = 0; e < 8; ++e)
        v[e] = f2b(W[((size_t)o * Cin + cb + e) * 9 + tap]);
    *(uint4*)&Wf[(size_t)idx * 8] = *(const uint4*)v;
}

// ---------- patch staging for conv ----------
template <int PR>
__device__ inline void stage_patch(const us* __restrict__ Xb, us* __restrict__ dst,
                                   int pyb, int kb, int Cin, int IH, int IW, int t) {
    const int ITEMS = (2 * PR + 2) * 36 * 4;
    for (int i = t; i < ITEMS; i += 256) {
        int p = i >> 2, q8 = (i & 3) * 8;
        int r = p / 36, x = p - r * 36;
        int gy = pyb + r;
        uint4 v = make_uint4(0u, 0u, 0u, 0u);
        if (x < IW && gy < IH)
            v = *(const uint4*)&Xb[((size_t)(gy * IW + x)) * Cin + kb * 32 + q8];
        *(uint4*)&dst[p * 40 + q8] = v;
    }
}

// ---------- MFMA conv3x3 VALID, channel-major, dbuf patch, direct-global weights ----------
template <int PR>
__global__ __launch_bounds__(256) void conv_mf4_k(const us* __restrict__ X, long xbstride,
                                                  const us* __restrict__ Wf,
                                                  const float* __restrict__ bias,
                                                  us* __restrict__ Y, long ybstride,
                                                  int Cin, int O, int IH, int IW,
                                                  int OH, int OW) {
    __shared__ us patch[2][(2 * PR + 2) * 36 * 40];
    int bz = blockIdx.z;
    int obase = blockIdx.y * 64;
    int pyb = blockIdx.x * (2 * PR);
    const us* Xb = X + (size_t)bz * xbstride;
    int t = threadIdx.x;
    int wave = t >> 6, lane = t & 63, lm = lane & 15, q = lane >> 4;
    int half = wave >> 1, rw = wave & 1;
    int KB = Cin >> 5;
    const us* Wb = Wf + (size_t)(obase >> 6) * KB * 9 * 2048;

    f32x4 acc[PR][2][2];
    #pragma unroll
    for (int pr = 0; pr < PR; ++pr)
        #pragma unroll
        for (int i = 0; i < 2; ++i)
            #pragma unroll
            for (int j = 0; j < 2; ++j) acc[pr][i][j] = (f32x4){0.f, 0.f, 0.f, 0.f};

    stage_patch<PR>(Xb, patch[0], pyb, 0, Cin, IH, IW, t);
    __syncthreads();
    int cur = 0;
    for (int kb = 0; kb < KB; ++kb) {
        if (kb + 1 < KB) stage_patch<PR>(Xb, patch[cur ^ 1], pyb, kb + 1, Cin, IH, IW, t);
        const us* Wk = Wb + (size_t)kb * 9 * 2048;
        #pragma unroll
        for (int tap = 0; tap < 9; ++tap) {
            int ky = tap / 3, kx = tap - ky * 3;
            const us* wt = Wk + tap * 2048 + half * 1024;
            short8 a0 = *(const short8*)&wt[lane * 8];
            short8 a1 = *(const short8*)&wt[512 + lane * 8];
            #pragma unroll
            for (int pr = 0; pr < PR; ++pr) {
                int prow = (pr * 2 + rw + ky) * 36;
                short8 b0 = *(const short8*)&patch[cur][(prow + lm + kx) * 40 + q * 8];
                short8 b1 = *(const short8*)&patch[cur][(prow + 16 + lm + kx) * 40 + q * 8];
                acc[pr][0][0] = MFMA16(a0, b0, acc[pr][0][0], 0, 0, 0);
                acc[pr][0][1] = MFMA16(a0, b1, acc[pr][0][1], 0, 0, 0);
                acc[pr][1][0] = MFMA16(a1, b0, acc[pr][1][0], 0, 0, 0);
                acc[pr][1][1] = MFMA16(a1, b1, acc[pr][1][1], 0, 0, 0);
            }
        }
        __syncthreads();
        cur ^= 1;
    }

    us* Yb = Y + (size_t)bz * ybstride;
    #pragma unroll
    for (int pr = 0; pr < PR; ++pr) {
        int py = pyb + pr * 2 + rw;
        if (py >= OH) continue;
        #pragma unroll
        for (int i = 0; i < 2; ++i) {
            int m0 = obase + half * 32 + i * 16 + q * 4;
            #pragma unroll
            for (int j = 0; j < 2; ++j) {
                int px = j * 16 + lm;
                if (px >= OW) continue;
                us o4[4];
                #pragma unroll
                for (int r = 0; r < 4; ++r) {
                    float v = acc[pr][i][j][r] + bias[m0 + r];
                    v = (v > 0.f) ? v : 0.f;
                    o4[r] = f2b(v);
                }
                *(uint2*)&Yb[((size_t)(py * OW + px)) * O + m0] = *(const uint2*)o4;
            }
        }
    }
}

// ---------- legacy 32x32 fp32 GEMM (w_fc, N=16) ----------
__global__ __launch_bounds__(256) void gemm_k(const float* __restrict__ W,
                                              const float* __restrict__ X,
                                              const float* __restrict__ bias,
                                              float* __restrict__ Y,
                                              int C, int O, int N) {
    int obase = blockIdx.y * 32;
    __shared__ float As[32][33];
    __shared__ float Bs[32][33];
    int t = threadIdx.x;
    int tx = t & 15, ty = t >> 4;
    float acc00 = 0, acc01 = 0, acc10 = 0, acc11 = 0;
    for (int cb = 0; cb < C; cb += 32) {
        int k = t & 31, o0 = t >> 5;
        #pragma unroll
        for (int r = 0; r < 4; ++r) {
            int ol = o0 + r * 8;
            As[k][ol] = W[(size_t)(obase + ol) * C + cb + k];
        }
        int n0 = t & 31, k0 = t >> 5;
        #pragma unroll
        for (int r = 0; r < 4; ++r) {
            int k2 = k0 + r * 8;
            Bs[k2][n0] = (n0 < N) ? X[(size_t)(cb + k2) * N + n0] : 0.f;
        }
        __syncthreads();
        #pragma unroll
        for (int k2 = 0; k2 < 32; ++k2) {
            float a0 = As[k2][ty], a1 = As[k2][ty + 16];
            float b0 = Bs[k2][tx], b1 = Bs[k2][tx + 16];
            acc00 += a0 * b0; acc01 += a0 * b1;
            acc10 += a1 * b0; acc11 += a1 * b1;
        }
        __syncthreads();
    }
    float accs[2][2] = {{acc00, acc01}, {acc10, acc11}};
    #pragma unroll
    for (int i = 0; i < 2; ++i) {
        int o = obase + ty + i * 16;
        float bv = bias[o];
        #pragma unroll
        for (int j = 0; j < 2; ++j) {
            int n = tx + j * 16;
            if (n < N) Y[(size_t)o * N + n] = accs[i][j] + bv;
        }
    }
}

// ---------- FC_S two-stage: partial sums of g^2 then combine ----------
__global__ __launch_bounds__(256) void fcs3a_k(const us* __restrict__ g, int ldg,
                                               float* __restrict__ pa, int HW) {
    int b = blockIdx.x, j = blockIdx.y;  // grid (B, 8)
    int t = threadIdx.x;
    const us* gb = g + ((size_t)b * HW + (size_t)j * 128) * ldg + 2 * t;
    double s0 = 0.0, s1 = 0.0;
    #pragma unroll 4
    for (int hw = 0; hw < 128; ++hw) {
        unsigned u = *(const unsigned*)&gb[(size_t)hw * ldg];
        float f0 = b2f((us)(u & 0xFFFFu));
        float f1 = b2f((us)(u >> 16));
        s0 += (double)f0 * (double)f0;
        s1 += (double)f1 * (double)f1;
    }
    float2 w = make_float2((float)s0, (float)s1);
    *(float2*)&pa[((size_t)b * 8 + j) * 512 + 2 * t] = w;
}

__global__ __launch_bounds__(256) void fcs3b_k(const float* __restrict__ pa,
                                               const float* __restrict__ bg,
                                               float* __restrict__ fcs, int B, int HW) {
    int b = blockIdx.x;
    int t = threadIdx.x;
    double s0 = 0.0, s1 = 0.0;
    #pragma unroll
    for (int j = 0; j < 8; ++j) {
        float2 w = *(const float2*)&pa[((size_t)b * 8 + j) * 512 + 2 * t];
        s0 += (double)w.x; s1 += (double)w.y;
    }
    int c0 = 2 * t;
    fcs[(size_t)c0 * B + b] = (float)(s0 / ((double)HW * (double)bg[c0]));
    fcs[(size_t)(c0 + 1) * B + b] = (float)(s1 / ((double)HW * (double)bg[c0 + 1]));
}

// ---------- covariance from fs [b][784][32] fp32 ----------
__global__ __launch_bounds__(256) void cov2_k(const float* __restrict__ fs,
                                              float* __restrict__ cov, int Cd, int M) {
    __shared__ float Ls[196 * 36];
    int bb = blockIdx.x;
    int t = threadIdx.x;
    const float* p = fs + (size_t)bb * M * Cd;
    int c = t >> 3, d0 = (t & 7) * 4;
    float a0 = 0.f, a1 = 0.f, a2 = 0.f, a3 = 0.f;
    for (int ch = 0; ch < 4; ++ch) {
        __syncthreads();
        for (int i = t; i < 1568; i += 256) {
            int rowi = i >> 3, c4 = (i & 7) * 4;
            float4 v = *(const float4*)&p[(size_t)(ch * 196 + rowi) * Cd + c4];
            *(float4*)&Ls[rowi * 36 + c4] = v;
        }
        __syncthreads();
        for (int i = 0; i < 196; ++i) {
            float a = Ls[i * 36 + c];
            a0 += a * Ls[i * 36 + d0 + 0];
            a1 += a * Ls[i * 36 + d0 + 1];
            a2 += a * Ls[i * 36 + d0 + 2];
            a3 += a * Ls[i * 36 + d0 + 3];
        }
    }
    float invM = 1.f / (float)M;
    size_t base = ((size_t)bb * Cd + c) * Cd + d0;
    cov[base + 0] = a0 * invM;
    cov[base + 1] = a1 * invM;
    cov[base + 2] = a2 * invM;
    cov[base + 3] = a3 * invM;
}

// ---------- fused epilogue over [b][token][c]; ffc has row stride ldf ----------
__global__ __launch_bounds__(256) void fuse_k(const us* __restrict__ ffc, int ldf,
                                              const float* __restrict__ fc2t,
                                              const us* __restrict__ p2,
                                              const us* __restrict__ p3,
                                              us* __restrict__ out, int B, int C, int HW) {
    size_t idx = (size_t)blockIdx.x * 256 + threadIdx.x;
    size_t total = (size_t)B * C * HW;
    if (idx >= total) return;
    int c = (int)(idx & (size_t)(C - 1));
    size_t tok = idx >> 9;                  // b*HW + hw
    int b = (int)(idx / ((size_t)C * HW));
    float part1 = b2f(ffc[tok * ldf + c]) * fc2t[(size_t)c * B + b];
    float v = part1 * b2f(p2[idx]) * b2f(p3[idx]);
    v = (v > 0.f) ? v : 0.f;
    out[idx] = f2b(cbrtf(v));
}

// ---------- launch ----------
extern "C" void kernel_launch(void* const* d_in, const int* in_sizes, int n_in,
                              void* d_out, int out_size, void* d_ws, size_t ws_size,
                              hipStream_t stream) {
    typedef const float* fp;
    fp content = (fp)d_in[0];
    fp style   = (fp)d_in[1];
    fp wf_san = (fp)d_in[2],  bf_san = (fp)d_in[3];
    fp wg_san = (fp)d_in[4],  bg_san = (fp)d_in[5];
    fp wh_san = (fp)d_in[6],  bh_san = (fp)d_in[7];
    fp wf_mcc = (fp)d_in[8],  bf_mcc = (fp)d_in[9];
    fp wg_mcc = (fp)d_in[10], bg_mcc = (fp)d_in[11];
    fp w_fc   = (fp)d_in[12], b_fc   = (fp)d_in[13];
    fp w_out  = (fp)d_in[14], b_out  = (fp)d_in[15];
    fp wc1 = (fp)d_in[16], bc1 = (fp)d_in[17];
    fp wc2 = (fp)d_in[18], bc2 = (fp)d_in[19];
    fp wc3 = (fp)d_in[20], bc3 = (fp)d_in[21];
    fp ws1 = (fp)d_in[22], bs1 = (fp)d_in[23];
    fp ws2 = (fp)d_in[24], bs2 = (fp)d_in[25];
    fp ws3 = (fp)d_in[26], bs3 = (fp)d_in[27];
    fp w_unc = (fp)d_in[28], b_unc = (fp)d_in[29];

    const int B = 16, C = 512, HW = 1024;
    const size_t NE = (size_t)B * C * HW;       // 8388608
    const long TOK = (long)C * HW;              // 524288 per-batch elems
    const size_t MB = 1u << 20;
    char* base = (char*)d_ws;

    // ---- time-multiplexed layout ----
    us* cnT      = (us*)(base);                 //   0- 16  (trn -> cn-stack)
    us* snT      = (us*)(base + 16 * MB);       //  16- 32  (trn -> sn-stack)
    us* fs0T     = (us*)(base + 32 * MB);       //  32- 48  (trn -> conv1)
    us* s1       = (us*)(base + 48 * MB);       //  48- 56  (conv1 -> conv2)
    us* s2       = (us*)(base + 56 * MB);       //  56- 60  (conv2 -> ws3)
    float* fs_c  = (float*)(base + 60 * MB);    //  60- 62  (ws3 -> cov2)
    us* Sbuf16   = (us*)(base);                 //   0- 32  fp16 logits (cnT/snT dead)
    h16* Sh      = (h16*)(base);
    us* cnOut    = (us*)(base + 64 * MB);       //  64-104  [b][hw][1280]
    us* snOut    = (us*)(base + 104 * MB);      // 104-136  [b][hw][1024] (-> logits)
    us* part3b   = (us*)(base + 104 * MB);      // 104-120  (softpv -> fuse)
    us* part2b   = (us*)(base + 120 * MB);      // 120-136  (part2 -> fuse)
    us* t2b      = (us*)(base + 136 * MB);      // 136-140
    float* fc_c  = (float*)(base + 140 * MB);   // 140-142
    float* out32 = (float*)(base + 142 * MB);   // 142-144
    us* pbuf     = (us*)(base + 144 * MB);      // 144-160  (fuse -> out)
    us* styleT   = (us*)(base + 168 * MB);      // 168-184  (trn -> H)
    us* Hco      = (us*)(base + 184 * MB);      // 184-200  (H -> softpv)

    char* misc = base + 200 * MB;
    us* Wr1   = (us*)(misc);                    // 2359296 B
    us* Wr2   = (us*)(misc + 2359296);          // 589824 B
    us* arena = (us*)(misc + 2949120);          // 3522560 B
    us* Wcn   = arena;                          // [1280][512]
    us* Wsn   = arena + 655360;                 // [1024][512]
    us* Wh    = arena + 1179648;                // [512][512]
    us* Wout  = arena + 1441792;                // [512][512]
    us* Wc2   = arena + 1703936;                // [128][256]
    us* Wc3   = arena + 1736704;                // [32][128]
    us* Ws3   = arena + 1740800;                // [32][128]
    us* Wunc  = arena + 1744896;                // [512][32]
    float* pa    = (float*)(misc + 6471680);    // 262144 B
    float* fcs   = (float*)(misc + 6733824);
    float* fc2t  = (float*)(misc + 6766592);
    float* cov   = (float*)(misc + 6799360);
    float* meanC = (float*)(misc + 6864896);
    float* invC  = (float*)(misc + 6897664);
    float* meanS = (float*)(misc + 6930432);
    float* invS  = (float*)(misc + 6963200);
    float* mrow  = (float*)(misc + 6995968);    // 65536 B
    float* ilrow = (float*)(misc + 7061504);    // 65536 B

    // 0: weight conversions
    CpyArg ca;
    const float* srcs[11] = {wf_mcc, wc1, wf_san, wg_mcc, wg_san, wh_san,
                             w_out, wc2, wc3, ws3, w_unc};
    int lens[11] = {262144, 131072, 262144, 262144, 262144, 262144,
                    262144, 32768, 4096, 4096, 16384};
    unsigned long long off = 0;
    for (int i = 0; i < 11; ++i) { ca.src[i] = srcs[i]; ca.dstoff[i] = off; ca.len[i] = lens[i]; off += lens[i]; }
    wcat_k<<<dim3(1024, 11), 256, 0, stream>>>(ca, arena);
    reorder_wf_k<<<576, 256, 0, stream>>>(ws1, Wr1, 256, 512);
    reorder_wf_k<<<72, 256, 0, stream>>>(ws2, Wr2, 128, 256);

    // 1: stats; bf16 transposes
    stats_k<<<B * C, 256, 0, stream>>>(content, meanC, invC, HW);
    stats_k<<<B * C, 256, 0, stream>>>(style, meanS, invS, HW);
    trn_k<<<dim3(16, 8, 16), 256, 0, stream>>>(content, meanC, invC, cnT, nullptr, nullptr, C, HW);
    trn_k<<<dim3(16, 8, 16), 256, 0, stream>>>(style, meanS, invS, snT, fs0T, styleT, C, HW);

    // 2: conv chain immediately (fs0T L3-hot)
    conv_mf4_k<1><<<dim3(15, 4, 16), 256, 0, stream>>>(fs0T, TOK, Wr1, bs1,
                                                       s1, (long)900 * 256, 512, 256, 32, 32, 30, 30);
    conv_mf4_k<1><<<dim3(14, 2, 16), 256, 0, stream>>>(s1, (long)900 * 256, Wr2, bs2,
                                                       s2, (long)784 * 128, 256, 128, 30, 30, 28, 28);
    mf2_k<us, us, float, 1><<<dim3(7, 1, 16), 256, 0, stream>>>(
        Ws3, 0, 128, s2, (long)784 * 128, 128, bs3, fs_c, nullptr, 128, 32, 784, 0);
    cov2_k<<<B, 256, 0, stream>>>(fs_c, cov, 32, 784);

    // 3: cn-stack GEMM -> cnOut [b][hw][{ffc:0-511, t1:512-767(relu), F:768-1279}]
    {
        SBias sb;
        for (int y = 0; y < 4; ++y) { sb.bp[y] = bf_mcc; sb.moff[y] = 0; }
        for (int y = 4; y < 6; ++y) { sb.bp[y] = bc1; sb.moff[y] = 512; }
        for (int y = 6; y < 10; ++y) { sb.bp[y] = bf_san; sb.moff[y] = 768; }
        sb.relu = 0x030u;  // t1 blocks only
        mfs_k<<<dim3(8, 10, 16), 256, 0, stream>>>(Wcn, cnT, TOK, 512, cnOut, 1280, sb, 512, 1024);
    }

    // 4: sn-stack GEMM -> snOut [b][hw][{g:0-511, G:512-1023}]
    {
        SBias sb;
        for (int y = 0; y < 4; ++y) { sb.bp[y] = bg_mcc; sb.moff[y] = 0; }
        for (int y = 4; y < 8; ++y) { sb.bp[y] = bg_san; sb.moff[y] = 512; }
        for (int y = 8; y < 10; ++y) { sb.bp[y] = bg_mcc; sb.moff[y] = 0; }
        sb.relu = 0u;
        mfs_k<<<dim3(8, 8, 16), 256, 0, stream>>>(Wsn, snT, TOK, 512, snOut, 1024, sb, 512, 1024);
    }

    // 5: FC_S (analytic denominator) two-stage; fc2t
    fcs3a_k<<<dim3(B, 8), 256, 0, stream>>>(snOut, 1024, pa, HW);
    fcs3b_k<<<B, 256, 0, stream>>>(pa, bg_mcc, fcs, B, HW);
    gemm_k<<<dim3(1, 16, 1), 256, 0, stream>>>(w_fc, fcs, b_fc, fc2t, 512, 512, 16);

    // 6: H = wh_san . style (styleT L3-warm)
    mf2_k<us, us, us, 0><<<dim3(8, 4, 16), 256, 0, stream>>>(
        Wh, 0, 512, styleT, TOK, 512, bh_san, Hco, nullptr, 512, 512, 1024, 0);

    // 7: logits S[i][j] = F . G -> fp16 (cnT/snT regions dead)
    mf2_k<us, us, h16, 0><<<dim3(8, 8, 16), 256, 0, stream>>>(
        cnOut + 768, (long)1024 * 1280, 1280, snOut + 512, (long)1024 * 1024, 1024,
        nullptr, Sh, nullptr, 512, 1024, 1024, 0);

    // 8: row stats (m, 1/l); fused softmax+PV -> part3 [b][i][c]
    rowstat_k<<<B * HW / 4, 256, 0, stream>>>(Sbuf16, mrow, ilrow);
    softpv_k<<<dim3(4, 8, 16), 256, 0, stream>>>(Sbuf16, mrow, ilrow, Hco, part3b);

    // 9: fc chain tail: t2 = relu(wc2 . t1); fc_c = wc3 . t2
    mf2_k<us, us, us, 1><<<dim3(8, 1, 16), 256, 0, stream>>>(
        Wc2, 0, 256, cnOut + 512, (long)1024 * 1280, 1280, bc2, t2b, nullptr, 256, 128, 1024, 1);
    mf2_k<us, us, float, 1><<<dim3(8, 1, 16), 256, 0, stream>>>(
        Wc3, 0, 128, t2b, (long)1024 * 128, 128, bc3, fc_c, nullptr, 128, 32, 1024, 0);

    // 10: out32 = cov . fc_c; part2 = w_unc . out32
    mf2_k<float, float, float, 1><<<dim3(8, 1, 16), 256, 0, stream>>>(
        cov, 1024, 32, fc_c, (long)1024 * 32, 32, nullptr, out32, nullptr, 32, 32, 1024, 0);
    mf2_k<us, float, us, 1><<<dim3(8, 4, 16), 256, 0, stream>>>(
        Wunc, 0, 32, out32, (long)1024 * 32, 32, b_unc, part2b, nullptr, 32, 512, 1024, 0);

    // 11: p = cbrt(relu(part1*part2*part3))
    fuse_k<<<(unsigned)((NE + 255) / 256), 256, 0, stream>>>(
        cnOut, 1280, fc2t, part2b, part3b, pbuf, B, C, HW);

    // 12: out = w_out . p + b_out + content -> d_out fp32 [b][o][hw]
    mf2_k<us, us, float, 0><<<dim3(8, 4, 16), 256, 0, stream>>>(
        Wout, 0, 512, pbuf, TOK, 512, b_out, (float*)d_out, content, 512, 512, 1024, 0);
}

// Round 7
// 783.151 us; speedup vs baseline: 1.0659x; 1.0659x over previous
//
#include <hip/hip_runtime.h>
#include <hip/hip_bf16.h>
#include <math.h>

// Channel-major ([b][hw][c]) MFMA bf16 pipeline, fp32 accumulate.
// - g-branch: numerator sum(g^2) via bf16 MFMA; denominator analytic (sum_hw sn == 0).
// - conv3x3: weights fragment-major, direct global->VGPR; patch LDS double-buffered.
// - All MFMA GEMMs double-buffer LDS (1 barrier/K-step).
// - Attention: fp32 logits + one-pass softmax + bf16 part3 GEMM (round-4 proven;
//   fp16-logits & fused-softpv measured +55-65 us regression in r5/r6).
// - part3 computed operand-swapped (A=H, B=P, OUTT=1) for vectorized 8B writes.

typedef __attribute__((ext_vector_type(8))) short short8;
typedef __attribute__((ext_vector_type(4))) float f32x4;
typedef unsigned short us;
#define MFMA16 __builtin_amdgcn_mfma_f32_16x16x32_bf16

__device__ inline float b2f(us b) { return __uint_as_float(((unsigned)b) << 16); }
__device__ inline us f2b(float f) {
    unsigned u = __float_as_uint(f);
    return (us)((u + 0x7FFFu + ((u >> 16) & 1u)) >> 16);
}

__device__ inline double blockReduceSumD(double v, double* sh) {
    int t = threadIdx.x;
    sh[t] = v; __syncthreads();
    for (int s = blockDim.x >> 1; s > 0; s >>= 1) {
        if (t < s) sh[t] += sh[t + s];
        __syncthreads();
    }
    double r = sh[0]; __syncthreads();
    return r;
}

// ---------- per-(b,c) spatial stats ----------
__global__ __launch_bounds__(256) void stats_k(const float* __restrict__ X,
                                               float* __restrict__ mean,
                                               float* __restrict__ inv, int HW) {
    __shared__ double sh[256];
    int bc = blockIdx.x;
    const float* x = X + (size_t)bc * HW;
    int t = threadIdx.x;
    float v[4];
    double s = 0.0;
    #pragma unroll
    for (int r = 0; r < 4; ++r) { v[r] = x[t + r * 256]; s += (double)v[r]; }
    double tot = blockReduceSumD(s, sh);
    double ss = 0.0;
    #pragma unroll
    for (int r = 0; r < 4; ++r) ss += (double)v[r] * (double)v[r];
    double tot2 = blockReduceSumD(ss, sh);
    if (t == 0) {
        double m = tot / HW;
        double var = (tot2 - tot * tot / HW) / (HW - 1);
        mean[bc] = (float)m;
        inv[bc] = (float)(1.0 / sqrt(var + 1e-5));
    }
}

// ---------- transpose [b][C][HW] fp32 -> up to 3 bf16 [b][HW][C] outputs ----------
__global__ __launch_bounds__(256) void trn_k(const float* __restrict__ X,
                                             const float* __restrict__ mean,
                                             const float* __restrict__ inv,
                                             us* __restrict__ Yn, us* __restrict__ Yc,
                                             us* __restrict__ Yr, int C, int HW) {
    __shared__ us Ln[64 * 65];
    __shared__ us Lc[64 * 65];
    __shared__ us Lr[64 * 65];
    int bz = blockIdx.z, c0 = blockIdx.y * 64, h0 = blockIdx.x * 64;
    const float* Xb = X + (size_t)bz * C * HW;
    int t = threadIdx.x;
    int cl = t >> 3, h8 = (t & 7) * 8;
    #pragma unroll
    for (int half = 0; half < 2; ++half) {
        int c = cl + half * 32;
        int gc = c0 + c;
        float m = mean[bz * C + gc], iv = inv[bz * C + gc];
        const float4* s4 = (const float4*)&Xb[(size_t)gc * HW + h0 + h8];
        float4 f0 = s4[0], f1 = s4[1];
        float vv[8] = {f0.x, f0.y, f0.z, f0.w, f1.x, f1.y, f1.z, f1.w};
        #pragma unroll
        for (int i = 0; i < 8; ++i) {
            int li = c * 65 + h8 + i;
            if (Yn) Ln[li] = f2b((vv[i] - m) * iv);
            if (Yc) Lc[li] = f2b(vv[i] - m);
            if (Yr) Lr[li] = f2b(vv[i]);
        }
    }
    __syncthreads();
    int hl = t >> 3, c8 = (t & 7) * 8;
    #pragma unroll
    for (int half = 0; half < 2; ++half) {
        int hh = hl + half * 32;
        size_t off = ((size_t)bz * HW + h0 + hh) * (size_t)C + c0 + c8;
        us tmp[8];
        if (Yn) {
            #pragma unroll
            for (int i = 0; i < 8; ++i) tmp[i] = Ln[(c8 + i) * 65 + hh];
            *(uint4*)&Yn[off] = *(const uint4*)tmp;
        }
        if (Yc) {
            #pragma unroll
            for (int i = 0; i < 8; ++i) tmp[i] = Lc[(c8 + i) * 65 + hh];
            *(uint4*)&Yc[off] = *(const uint4*)tmp;
        }
        if (Yr) {
            #pragma unroll
            for (int i = 0; i < 8; ++i) tmp[i] = Lr[(c8 + i) * 65 + hh];
            *(uint4*)&Yr[off] = *(const uint4*)tmp;
        }
    }
}

// ---------- staging: 16 k-contiguous elems -> bf16 LDS ----------
template <typename TE>
__device__ inline void stage16(const TE* __restrict__ src, bool valid, us* dst) {
    us tmp[16];
    if (valid) {
        if constexpr (sizeof(TE) == 2) {
            uint4 a = ((const uint4*)src)[0], b = ((const uint4*)src)[1];
            *(uint4*)&tmp[0] = a; *(uint4*)&tmp[8] = b;
        } else {
            const float4* s4 = (const float4*)src;
            float4 f0 = s4[0], f1 = s4[1], f2 = s4[2], f3 = s4[3];
            float vv[16] = {f0.x, f0.y, f0.z, f0.w, f1.x, f1.y, f1.z, f1.w,
                            f2.x, f2.y, f2.z, f2.w, f3.x, f3.y, f3.z, f3.w};
            #pragma unroll
            for (int i = 0; i < 16; ++i) tmp[i] = f2b(vv[i]);
        }
    } else {
        #pragma unroll
        for (int i = 0; i < 16; ++i) tmp[i] = 0;
    }
    ((uint4*)dst)[0] = *(uint4*)&tmp[0];
    ((uint4*)dst)[1] = *(uint4*)&tmp[8];
}

// ---------- 128x128 MFMA GEMM, double-buffered LDS ----------
// acc[m][n] = sum_k A[m][k] * B[n][k]
// OUTT=0: Y[b][m][n] row-major (+add_src fp32); OUTT=1: Y[b][n][m]
template <typename TAel, typename TBel, typename TOUT, int OUTT>
__global__ __launch_bounds__(256) void mf2_k(const TAel* __restrict__ A, long astride, int lda,
                                             const TBel* __restrict__ B, long bstride, int ldb,
                                             const float* __restrict__ bias,
                                             TOUT* __restrict__ Y,
                                             const float* __restrict__ add_src,
                                             int K, int M, int N, int relu) {
    __shared__ us As[2][128][40];
    __shared__ us Bs[2][128][40];
    int bz = blockIdx.z;
    int mbase = blockIdx.y * 128, nbase = blockIdx.x * 128;
    const TAel* Ab = A + (size_t)bz * astride;
    const TBel* Bb = B + (size_t)bz * bstride;
    int t = threadIdx.x;
    int row = t & 127, kh = t >> 7;
    int wave = t >> 6, lane = t & 63, lm = lane & 15, q = lane >> 4;
    int mh = (wave >> 1) * 64, nh = (wave & 1) * 64;
    int gm = mbase + row, gn = nbase + row;
    bool vm = gm < M, vn = gn < N;

    auto stage = [&](int buf, int kb) {
        stage16(Ab + (size_t)gm * lda + kb + kh * 16, vm, &As[buf][row][kh * 16]);
        stage16(Bb + (size_t)gn * ldb + kb + kh * 16, vn, &Bs[buf][row][kh * 16]);
    };

    f32x4 acc[4][4];
    #pragma unroll
    for (int i = 0; i < 4; ++i)
        #pragma unroll
        for (int j = 0; j < 4; ++j) acc[i][j] = (f32x4){0.f, 0.f, 0.f, 0.f};

    stage(0, 0);
    __syncthreads();
    int cur = 0;
    for (int kb = 0; kb < K; kb += 32) {
        if (kb + 32 < K) stage(cur ^ 1, kb + 32);
        short8 af[4], bf[4];
        #pragma unroll
        for (int i = 0; i < 4; ++i) af[i] = *(const short8*)&As[cur][mh + i * 16 + lm][q * 8];
        #pragma unroll
        for (int j = 0; j < 4; ++j) bf[j] = *(const short8*)&Bs[cur][nh + j * 16 + lm][q * 8];
        #pragma unroll
        for (int i = 0; i < 4; ++i)
            #pragma unroll
            for (int j = 0; j < 4; ++j)
                acc[i][j] = MFMA16(af[i], bf[j], acc[i][j], 0, 0, 0);
        __syncthreads();
        cur ^= 1;
    }

    #pragma unroll
    for (int i = 0; i < 4; ++i) {
        int m0 = mbase + mh + i * 16 + q * 4;
        if (m0 >= M) continue;
        float bv[4];
        #pragma unroll
        for (int r = 0; r < 4; ++r) bv[r] = bias ? bias[m0 + r] : 0.f;
        #pragma unroll
        for (int j = 0; j < 4; ++j) {
            int n = nbase + nh + j * 16 + lm;
            if (n >= N) continue;
            float v[4];
            #pragma unroll
            for (int r = 0; r < 4; ++r) {
                float x = acc[i][j][r] + bv[r];
                if (relu) x = (x > 0.f) ? x : 0.f;
                v[r] = x;
            }
            if (OUTT == 1) {
                size_t off = ((size_t)bz * N + n) * (size_t)M + m0;
                if constexpr (sizeof(TOUT) == 2) {
                    us o4[4];
                    #pragma unroll
                    for (int r = 0; r < 4; ++r) o4[r] = f2b(v[r]);
                    *(uint2*)&Y[off] = *(const uint2*)o4;
                } else {
                    float4 f4 = make_float4(v[0], v[1], v[2], v[3]);
                    *(float4*)&Y[off] = f4;
                }
            } else {
                #pragma unroll
                for (int r = 0; r < 4; ++r) {
                    size_t off = ((size_t)bz * M + m0 + r) * (size_t)N + n;
                    float x = v[r];
                    if (add_src) x += add_src[off];
                    if constexpr (sizeof(TOUT) == 2) Y[off] = f2b(x);
                    else Y[off] = x;
                }
            }
        }
    }
}

// ---------- stacked-M MFMA GEMM (dbuf): A bf16 [Mstack][K], out [b][n][Mstack] ----------
struct SBias {
    const float* bp[10];
    int moff[10];
    unsigned relu;
};
__global__ __launch_bounds__(256) void mfs_k(const us* __restrict__ A,
                                             const us* __restrict__ B, long bstride, int ldb,
                                             us* __restrict__ Y, int ldy,
                                             SBias sb, int K, int N) {
    __shared__ us As[2][128][40];
    __shared__ us Bs[2][128][40];
    int bz = blockIdx.z;
    int mbase = blockIdx.y * 128, nbase = blockIdx.x * 128;
    const us* Bb = B + (size_t)bz * bstride;
    int t = threadIdx.x;
    int row = t & 127, kh = t >> 7;
    int wave = t >> 6, lane = t & 63, lm = lane & 15, q = lane >> 4;
    int mh = (wave >> 1) * 64, nh = (wave & 1) * 64;
    int relu = (sb.relu >> blockIdx.y) & 1;
    const float* bias = sb.bp[blockIdx.y];
    int moff = sb.moff[blockIdx.y];

    auto stage = [&](int buf, int kb) {
        stage16(A + (size_t)(mbase + row) * K + kb + kh * 16, true, &As[buf][row][kh * 16]);
        stage16(Bb + (size_t)(nbase + row) * ldb + kb + kh * 16, true, &Bs[buf][row][kh * 16]);
    };

    f32x4 acc[4][4];
    #pragma unroll
    for (int i = 0; i < 4; ++i)
        #pragma unroll
        for (int j = 0; j < 4; ++j) acc[i][j] = (f32x4){0.f, 0.f, 0.f, 0.f};

    stage(0, 0);
    __syncthreads();
    int cur = 0;
    for (int kb = 0; kb < K; kb += 32) {
        if (kb + 32 < K) stage(cur ^ 1, kb + 32);
        short8 af[4], bf[4];
        #pragma unroll
        for (int i = 0; i < 4; ++i) af[i] = *(const short8*)&As[cur][mh + i * 16 + lm][q * 8];
        #pragma unroll
        for (int j = 0; j < 4; ++j) bf[j] = *(const short8*)&Bs[cur][nh + j * 16 + lm][q * 8];
        #pragma unroll
        for (int i = 0; i < 4; ++i)
            #pragma unroll
            for (int j = 0; j < 4; ++j)
                acc[i][j] = MFMA16(af[i], bf[j], acc[i][j], 0, 0, 0);
        __syncthreads();
        cur ^= 1;
    }

    #pragma unroll
    for (int i = 0; i < 4; ++i) {
        int m0 = mbase + mh + i * 16 + q * 4;
        float bv[4];
        #pragma unroll
        for (int r = 0; r < 4; ++r) bv[r] = bias[m0 - moff + r];
        #pragma unroll
        for (int j = 0; j < 4; ++j) {
            int n = nbase + nh + j * 16 + lm;
            us o4[4];
            #pragma unroll
            for (int r = 0; r < 4; ++r) {
                float x = acc[i][j][r] + bv[r];
                if (relu) x = (x > 0.f) ? x : 0.f;
                o4[r] = f2b(x);
            }
            *(uint2*)&Y[((size_t)bz * N + n) * ldy + m0] = *(const uint2*)o4;
        }
    }
}

// ---------- weight concat/convert fp32 -> bf16 arena ----------
struct CpyArg {
    const float* src[11];
    unsigned long long dstoff[11];
    int len[11];
};
__global__ __launch_bounds__(256) void wcat_k(CpyArg a, us* __restrict__ arena) {
    int seg = blockIdx.y;
    int idx = blockIdx.x * 256 + threadIdx.x;
    if (idx < a.len[seg]) arena[a.dstoff[seg] + idx] = f2b(a.src[seg][idx]);
}

// ---------- conv3x3 weight reorder: fragment-major ----------
__global__ __launch_bounds__(256) void reorder_wf_k(const float* __restrict__ W,
                                                    us* __restrict__ Wf, int O, int Cin) {
    int idx = blockIdx.x * 256 + threadIdx.x;
    int OT = O >> 6, KB = Cin >> 5;
    int total = OT * KB * 9 * 4 * 64;
    if (idx >= total) return;
    int lane = idx & 63;
    int f = idx >> 6;
    int i = f & 1, half = (f >> 1) & 1;
    int tf = f >> 2;
    int tap = tf % 9;
    int rest = tf / 9;
    int kb = rest % KB, ot = rest / KB;
    int o = ot * 64 + half * 32 + i * 16 + (lane & 15);
    int cb = kb * 32 + (lane >> 4) * 8;
    us v[8];
    #pragma unroll
    for (int e = 0; e < 8; ++e)
        v[e] = f2b(W[((size_t)o * Cin + cb + e) * 9 + tap]);
    *(uint4*)&Wf[(size_t)idx * 8] = *(const uint4*)v;
}

// ---------- patch staging for conv ----------
template <int PR>
__device__ inline void stage_patch(const us* __restrict__ Xb, us* __restrict__ dst,
                                   int pyb, int kb, int Cin, int IH, int IW, int t) {
    const int ITEMS = (2 * PR + 2) * 36 * 4;
    for (int i = t; i < ITEMS; i += 256) {
        int p = i >> 2, q8 = (i & 3) * 8;
        int r = p / 36, x = p - r * 36;
        int gy = pyb + r;
        uint4 v = make_uint4(0u, 0u, 0u, 0u);
        if (x < IW && gy < IH)
            v = *(const uint4*)&Xb[((size_t)(gy * IW + x)) * Cin + kb * 32 + q8];
        *(uint4*)&dst[p * 40 + q8] = v;
    }
}

// ---------- MFMA conv3x3 VALID, channel-major, dbuf patch, direct-global weights ----------
template <int PR>
__global__ __launch_bounds__(256) void conv_mf4_k(const us* __restrict__ X, long xbstride,
                                                  const us* __restrict__ Wf,
                                                  const float* __restrict__ bias,
                                                  us* __restrict__ Y, long ybstride,
                                                  int Cin, int O, int IH, int IW,
                                                  int OH, int OW) {
    __shared__ us patch[2][(2 * PR + 2) * 36 * 40];
    int bz = blockIdx.z;
    int obase = blockIdx.y * 64;
    int pyb = blockIdx.x * (2 * PR);
    const us* Xb = X + (size_t)bz * xbstride;
    int t = threadIdx.x;
    int wave = t >> 6, lane = t & 63, lm = lane & 15, q = lane >> 4;
    int half = wave >> 1, rw = wave & 1;
    int KB = Cin >> 5;
    const us* Wb = Wf + (size_t)(obase >> 6) * KB * 9 * 2048;

    f32x4 acc[PR][2][2];
    #pragma unroll
    for (int pr = 0; pr < PR; ++pr)
        #pragma unroll
        for (int i = 0; i < 2; ++i)
            #pragma unroll
            for (int j = 0; j < 2; ++j) acc[pr][i][j] = (f32x4){0.f, 0.f, 0.f, 0.f};

    stage_patch<PR>(Xb, patch[0], pyb, 0, Cin, IH, IW, t);
    __syncthreads();
    int cur = 0;
    for (int kb = 0; kb < KB; ++kb) {
        if (kb + 1 < KB) stage_patch<PR>(Xb, patch[cur ^ 1], pyb, kb + 1, Cin, IH, IW, t);
        const us* Wk = Wb + (size_t)kb * 9 * 2048;
        #pragma unroll
        for (int tap = 0; tap < 9; ++tap) {
            int ky = tap / 3, kx = tap - ky * 3;
            const us* wt = Wk + tap * 2048 + half * 1024;
            short8 a0 = *(const short8*)&wt[lane * 8];
            short8 a1 = *(const short8*)&wt[512 + lane * 8];
            #pragma unroll
            for (int pr = 0; pr < PR; ++pr) {
                int prow = (pr * 2 + rw + ky) * 36;
                short8 b0 = *(const short8*)&patch[cur][(prow + lm + kx) * 40 + q * 8];
                short8 b1 = *(const short8*)&patch[cur][(prow + 16 + lm + kx) * 40 + q * 8];
                acc[pr][0][0] = MFMA16(a0, b0, acc[pr][0][0], 0, 0, 0);
                acc[pr][0][1] = MFMA16(a0, b1, acc[pr][0][1], 0, 0, 0);
                acc[pr][1][0] = MFMA16(a1, b0, acc[pr][1][0], 0, 0, 0);
                acc[pr][1][1] = MFMA16(a1, b1, acc[pr][1][1], 0, 0, 0);
            }
        }
        __syncthreads();
        cur ^= 1;
    }

    us* Yb = Y + (size_t)bz * ybstride;
    #pragma unroll
    for (int pr = 0; pr < PR; ++pr) {
        int py = pyb + pr * 2 + rw;
        if (py >= OH) continue;
        #pragma unroll
        for (int i = 0; i < 2; ++i) {
            int m0 = obase + half * 32 + i * 16 + q * 4;
            #pragma unroll
            for (int j = 0; j < 2; ++j) {
                int px = j * 16 + lm;
                if (px >= OW) continue;
                us o4[4];
                #pragma unroll
                for (int r = 0; r < 4; ++r) {
                    float v = acc[pr][i][j][r] + bias[m0 + r];
                    v = (v > 0.f) ? v : 0.f;
                    o4[r] = f2b(v);
                }
                *(uint2*)&Yb[((size_t)(py * OW + px)) * O + m0] = *(const uint2*)o4;
            }
        }
    }
}

// ---------- legacy 32x32 fp32 GEMM (w_fc, N=16) ----------
__global__ __launch_bounds__(256) void gemm_k(const float* __restrict__ W,
                                              const float* __restrict__ X,
                                              const float* __restrict__ bias,
                                              float* __restrict__ Y,
                                              int C, int O, int N) {
    int obase = blockIdx.y * 32;
    __shared__ float As[32][33];
    __shared__ float Bs[32][33];
    int t = threadIdx.x;
    int tx = t & 15, ty = t >> 4;
    float acc00 = 0, acc01 = 0, acc10 = 0, acc11 = 0;
    for (int cb = 0; cb < C; cb += 32) {
        int k = t & 31, o0 = t >> 5;
        #pragma unroll
        for (int r = 0; r < 4; ++r) {
            int ol = o0 + r * 8;
            As[k][ol] = W[(size_t)(obase + ol) * C + cb + k];
        }
        int n0 = t & 31, k0 = t >> 5;
        #pragma unroll
        for (int r = 0; r < 4; ++r) {
            int k2 = k0 + r * 8;
            Bs[k2][n0] = (n0 < N) ? X[(size_t)(cb + k2) * N + n0] : 0.f;
        }
        __syncthreads();
        #pragma unroll
        for (int k2 = 0; k2 < 32; ++k2) {
            float a0 = As[k2][ty], a1 = As[k2][ty + 16];
            float b0 = Bs[k2][tx], b1 = Bs[k2][tx + 16];
            acc00 += a0 * b0; acc01 += a0 * b1;
            acc10 += a1 * b0; acc11 += a1 * b1;
        }
        __syncthreads();
    }
    float accs[2][2] = {{acc00, acc01}, {acc10, acc11}};
    #pragma unroll
    for (int i = 0; i < 2; ++i) {
        int o = obase + ty + i * 16;
        float bv = bias[o];
        #pragma unroll
        for (int j = 0; j < 2; ++j) {
            int n = tx + j * 16;
            if (n < N) Y[(size_t)o * N + n] = accs[i][j] + bv;
        }
    }
}

// ---------- FC_S two-stage: partial sums of g^2 then combine ----------
__global__ __launch_bounds__(256) void fcs3a_k(const us* __restrict__ g, int ldg,
                                               float* __restrict__ pa, int HW) {
    int b = blockIdx.x, j = blockIdx.y;  // grid (B, 8)
    int t = threadIdx.x;
    const us* gb = g + ((size_t)b * HW + (size_t)j * 128) * ldg + 2 * t;
    double s0 = 0.0, s1 = 0.0;
    #pragma unroll 4
    for (int hw = 0; hw < 128; ++hw) {
        unsigned u = *(const unsigned*)&gb[(size_t)hw * ldg];
        float f0 = b2f((us)(u & 0xFFFFu));
        float f1 = b2f((us)(u >> 16));
        s0 += (double)f0 * (double)f0;
        s1 += (double)f1 * (double)f1;
    }
    float2 w = make_float2((float)s0, (float)s1);
    *(float2*)&pa[((size_t)b * 8 + j) * 512 + 2 * t] = w;
}

__global__ __launch_bounds__(256) void fcs3b_k(const float* __restrict__ pa,
                                               const float* __restrict__ bg,
                                               float* __restrict__ fcs, int B, int HW) {
    int b = blockIdx.x;
    int t = threadIdx.x;
    double s0 = 0.0, s1 = 0.0;
    #pragma unroll
    for (int j = 0; j < 8; ++j) {
        float2 w = *(const float2*)&pa[((size_t)b * 8 + j) * 512 + 2 * t];
        s0 += (double)w.x; s1 += (double)w.y;
    }
    int c0 = 2 * t;
    fcs[(size_t)c0 * B + b] = (float)(s0 / ((double)HW * (double)bg[c0]));
    fcs[(size_t)(c0 + 1) * B + b] = (float)(s1 / ((double)HW * (double)bg[c0 + 1]));
}

// ---------- softmax fp32 -> bf16 P ----------
__global__ __launch_bounds__(256) void softmax_k(const float* __restrict__ S,
                                                 us* __restrict__ P) {
    __shared__ float sh[256];
    size_t row = blockIdx.x;
    const float* r = S + row * 1024;
    us* po = P + row * 1024;
    int t = threadIdx.x;
    float v[4];
    float m = -INFINITY;
    #pragma unroll
    for (int i = 0; i < 4; ++i) { v[i] = r[t + i * 256]; m = fmaxf(m, v[i]); }
    sh[t] = m; __syncthreads();
    for (int s = 128; s > 0; s >>= 1) { if (t < s) sh[t] = fmaxf(sh[t], sh[t + s]); __syncthreads(); }
    m = sh[0]; __syncthreads();
    float sum = 0;
    #pragma unroll
    for (int i = 0; i < 4; ++i) { v[i] = expf(v[i] - m); sum += v[i]; }
    sh[t] = sum; __syncthreads();
    for (int s = 128; s > 0; s >>= 1) { if (t < s) sh[t] += sh[t + s]; __syncthreads(); }
    float inv = 1.f / sh[0]; __syncthreads();
    #pragma unroll
    for (int i = 0; i < 4; ++i) po[t + i * 256] = f2b(v[i] * inv);
}

// ---------- covariance from fs [b][784][32] fp32 ----------
__global__ __launch_bounds__(256) void cov2_k(const float* __restrict__ fs,
                                              float* __restrict__ cov, int Cd, int M) {
    __shared__ float Ls[196 * 36];
    int bb = blockIdx.x;
    int t = threadIdx.x;
    const float* p = fs + (size_t)bb * M * Cd;
    int c = t >> 3, d0 = (t & 7) * 4;
    float a0 = 0.f, a1 = 0.f, a2 = 0.f, a3 = 0.f;
    for (int ch = 0; ch < 4; ++ch) {
        __syncthreads();
        for (int i = t; i < 1568; i += 256) {
            int rowi = i >> 3, c4 = (i & 7) * 4;
            float4 v = *(const float4*)&p[(size_t)(ch * 196 + rowi) * Cd + c4];
            *(float4*)&Ls[rowi * 36 + c4] = v;
        }
        __syncthreads();
        for (int i = 0; i < 196; ++i) {
            float a = Ls[i * 36 + c];
            a0 += a * Ls[i * 36 + d0 + 0];
            a1 += a * Ls[i * 36 + d0 + 1];
            a2 += a * Ls[i * 36 + d0 + 2];
            a3 += a * Ls[i * 36 + d0 + 3];
        }
    }
    float invM = 1.f / (float)M;
    size_t base = ((size_t)bb * Cd + c) * Cd + d0;
    cov[base + 0] = a0 * invM;
    cov[base + 1] = a1 * invM;
    cov[base + 2] = a2 * invM;
    cov[base + 3] = a3 * invM;
}

// ---------- fused epilogue over [b][token][c]; ffc has row stride ldf ----------
__global__ __launch_bounds__(256) void fuse_k(const us* __restrict__ ffc, int ldf,
                                              const float* __restrict__ fc2t,
                                              const us* __restrict__ p2,
                                              const us* __restrict__ p3,
                                              us* __restrict__ out, int B, int C, int HW) {
    size_t idx = (size_t)blockIdx.x * 256 + threadIdx.x;
    size_t total = (size_t)B * C * HW;
    if (idx >= total) return;
    int c = (int)(idx & (size_t)(C - 1));
    size_t tok = idx >> 9;                  // b*HW + hw
    int b = (int)(idx / ((size_t)C * HW));
    float part1 = b2f(ffc[tok * ldf + c]) * fc2t[(size_t)c * B + b];
    float v = part1 * b2f(p2[idx]) * b2f(p3[idx]);
    v = (v > 0.f) ? v : 0.f;
    out[idx] = f2b(cbrtf(v));
}

// ---------- launch ----------
extern "C" void kernel_launch(void* const* d_in, const int* in_sizes, int n_in,
                              void* d_out, int out_size, void* d_ws, size_t ws_size,
                              hipStream_t stream) {
    typedef const float* fp;
    fp content = (fp)d_in[0];
    fp style   = (fp)d_in[1];
    fp wf_san = (fp)d_in[2],  bf_san = (fp)d_in[3];
    fp wg_san = (fp)d_in[4],  bg_san = (fp)d_in[5];
    fp wh_san = (fp)d_in[6],  bh_san = (fp)d_in[7];
    fp wf_mcc = (fp)d_in[8],  bf_mcc = (fp)d_in[9];
    fp wg_mcc = (fp)d_in[10], bg_mcc = (fp)d_in[11];
    fp w_fc   = (fp)d_in[12], b_fc   = (fp)d_in[13];
    fp w_out  = (fp)d_in[14], b_out  = (fp)d_in[15];
    fp wc1 = (fp)d_in[16], bc1 = (fp)d_in[17];
    fp wc2 = (fp)d_in[18], bc2 = (fp)d_in[19];
    fp wc3 = (fp)d_in[20], bc3 = (fp)d_in[21];
    fp ws1 = (fp)d_in[22], bs1 = (fp)d_in[23];
    fp ws2 = (fp)d_in[24], bs2 = (fp)d_in[25];
    fp ws3 = (fp)d_in[26], bs3 = (fp)d_in[27];
    fp w_unc = (fp)d_in[28], b_unc = (fp)d_in[29];

    const int B = 16, C = 512, HW = 1024;
    const size_t NE = (size_t)B * C * HW;       // 8388608
    const long TOK = (long)C * HW;              // 524288 per-batch elems
    const size_t MB = 1u << 20;
    char* base = (char*)d_ws;

    // ---- time-multiplexed layout ----
    us* cnT      = (us*)(base);                 //   0- 16  (trn -> cn-stack)
    us* snT      = (us*)(base + 16 * MB);       //  16- 32  (trn -> sn-stack)
    us* fs0T     = (us*)(base + 32 * MB);       //  32- 48  (trn -> conv1)
    us* s1       = (us*)(base + 48 * MB);       //  48- 56  (conv1 -> conv2)
    us* s2       = (us*)(base + 56 * MB);       //  56- 60  (conv2 -> ws3)
    float* fs_c  = (float*)(base + 60 * MB);    //  60- 62  (ws3 -> cov2)
    float* Sbuf  = (float*)(base);              //   0- 64  logits (all above dead)
    us* cnOut    = (us*)(base + 64 * MB);       //  64-104  [b][hw][1280]
    us* snOut    = (us*)(base + 104 * MB);      // 104-136  [b][hw][1024] (-> logits)
    us* part3b   = (us*)(base + 104 * MB);      // 104-120  (part3 -> fuse)
    us* part2b   = (us*)(base + 120 * MB);      // 120-136  (part2 -> fuse)
    us* Pb       = (us*)(base + 136 * MB);      // 136-168  (softmax -> part3)
    us* t2b      = (us*)(base + 136 * MB);      // 136-140  (after Pb dead)
    float* fc_c  = (float*)(base + 140 * MB);   // 140-142
    float* out32 = (float*)(base + 142 * MB);   // 142-144
    us* pbuf     = (us*)(base + 144 * MB);      // 144-160  (fuse -> out)
    us* styleT   = (us*)(base + 168 * MB);      // 168-184  (trn -> H)
    us* Hco      = (us*)(base + 184 * MB);      // 184-200  (H -> part3)

    char* misc = base + 200 * MB;
    us* Wr1   = (us*)(misc);                    // 2359296 B
    us* Wr2   = (us*)(misc + 2359296);          // 589824 B
    us* arena = (us*)(misc + 2949120);          // 3522560 B
    us* Wcn   = arena;                          // [1280][512]
    us* Wsn   = arena + 655360;                 // [1024][512]
    us* Wh    = arena + 1179648;                // [512][512]
    us* Wout  = arena + 1441792;                // [512][512]
    us* Wc2   = arena + 1703936;                // [128][256]
    us* Wc3   = arena + 1736704;                // [32][128]
    us* Ws3   = arena + 1740800;                // [32][128]
    us* Wunc  = arena + 1744896;                // [512][32]
    float* pa    = (float*)(misc + 6471680);    // 262144 B
    float* fcs   = (float*)(misc + 6733824);
    float* fc2t  = (float*)(misc + 6766592);
    float* cov   = (float*)(misc + 6799360);
    float* meanC = (float*)(misc + 6864896);
    float* invC  = (float*)(misc + 6897664);
    float* meanS = (float*)(misc + 6930432);
    float* invS  = (float*)(misc + 6963200);

    // 0: weight conversions
    CpyArg ca;
    const float* srcs[11] = {wf_mcc, wc1, wf_san, wg_mcc, wg_san, wh_san,
                             w_out, wc2, wc3, ws3, w_unc};
    int lens[11] = {262144, 131072, 262144, 262144, 262144, 262144,
                    262144, 32768, 4096, 4096, 16384};
    unsigned long long off = 0;
    for (int i = 0; i < 11; ++i) { ca.src[i] = srcs[i]; ca.dstoff[i] = off; ca.len[i] = lens[i]; off += lens[i]; }
    wcat_k<<<dim3(1024, 11), 256, 0, stream>>>(ca, arena);
    reorder_wf_k<<<576, 256, 0, stream>>>(ws1, Wr1, 256, 512);
    reorder_wf_k<<<72, 256, 0, stream>>>(ws2, Wr2, 128, 256);

    // 1: stats; bf16 transposes
    stats_k<<<B * C, 256, 0, stream>>>(content, meanC, invC, HW);
    stats_k<<<B * C, 256, 0, stream>>>(style, meanS, invS, HW);
    trn_k<<<dim3(16, 8, 16), 256, 0, stream>>>(content, meanC, invC, cnT, nullptr, nullptr, C, HW);
    trn_k<<<dim3(16, 8, 16), 256, 0, stream>>>(style, meanS, invS, snT, fs0T, styleT, C, HW);

    // 2: conv chain immediately (fs0T L3-hot)
    conv_mf4_k<1><<<dim3(15, 4, 16), 256, 0, stream>>>(fs0T, TOK, Wr1, bs1,
                                                       s1, (long)900 * 256, 512, 256, 32, 32, 30, 30);
    conv_mf4_k<1><<<dim3(14, 2, 16), 256, 0, stream>>>(s1, (long)900 * 256, Wr2, bs2,
                                                       s2, (long)784 * 128, 256, 128, 30, 30, 28, 28);
    mf2_k<us, us, float, 1><<<dim3(7, 1, 16), 256, 0, stream>>>(
        Ws3, 0, 128, s2, (long)784 * 128, 128, bs3, fs_c, nullptr, 128, 32, 784, 0);
    cov2_k<<<B, 256, 0, stream>>>(fs_c, cov, 32, 784);

    // 3: cn-stack GEMM -> cnOut [b][hw][{ffc:0-511, t1:512-767(relu), F:768-1279}]
    {
        SBias sb;
        for (int y = 0; y < 4; ++y) { sb.bp[y] = bf_mcc; sb.moff[y] = 0; }
        for (int y = 4; y < 6; ++y) { sb.bp[y] = bc1; sb.moff[y] = 512; }
        for (int y = 6; y < 10; ++y) { sb.bp[y] = bf_san; sb.moff[y] = 768; }
        sb.relu = 0x030u;  // t1 blocks only
        mfs_k<<<dim3(8, 10, 16), 256, 0, stream>>>(Wcn, cnT, TOK, 512, cnOut, 1280, sb, 512, 1024);
    }

    // 4: sn-stack GEMM -> snOut [b][hw][{g:0-511, G:512-1023}]
    {
        SBias sb;
        for (int y = 0; y < 4; ++y) { sb.bp[y] = bg_mcc; sb.moff[y] = 0; }
        for (int y = 4; y < 8; ++y) { sb.bp[y] = bg_san; sb.moff[y] = 512; }
        for (int y = 8; y < 10; ++y) { sb.bp[y] = bg_mcc; sb.moff[y] = 0; }
        sb.relu = 0u;
        mfs_k<<<dim3(8, 8, 16), 256, 0, stream>>>(Wsn, snT, TOK, 512, snOut, 1024, sb, 512, 1024);
    }

    // 5: FC_S (analytic denominator) two-stage; fc2t
    fcs3a_k<<<dim3(B, 8), 256, 0, stream>>>(snOut, 1024, pa, HW);
    fcs3b_k<<<B, 256, 0, stream>>>(pa, bg_mcc, fcs, B, HW);
    gemm_k<<<dim3(1, 16, 1), 256, 0, stream>>>(w_fc, fcs, b_fc, fc2t, 512, 512, 16);

    // 6: H = wh_san . style (styleT L3-warm; independent of logits)
    mf2_k<us, us, us, 0><<<dim3(8, 4, 16), 256, 0, stream>>>(
        Wh, 0, 512, styleT, TOK, 512, bh_san, Hco, nullptr, 512, 512, 1024, 0);

    // 7: logits S[i][j] = F . G (fp32) ; softmax -> Pb
    mf2_k<us, us, float, 0><<<dim3(8, 8, 16), 256, 0, stream>>>(
        cnOut + 768, (long)1024 * 1280, 1280, snOut + 512, (long)1024 * 1024, 1024,
        nullptr, Sbuf, nullptr, 512, 1024, 1024, 0);
    softmax_k<<<B * HW, 256, 0, stream>>>(Sbuf, Pb);

    // 8: part3[b][i][c] = sum_j P[i][j] H[c][j] — operand-swapped (A=H, B=P),
    //    OUTT=1 writes [b][i][c] with vectorized uint2 stores; identical math.
    mf2_k<us, us, us, 1><<<dim3(8, 4, 16), 256, 0, stream>>>(
        Hco, TOK, 1024, Pb, (long)1024 * 1024, 1024, nullptr, part3b, nullptr,
        1024, 512, 1024, 0);

    // 9: fc chain tail: t2 = relu(wc2 . t1); fc_c = wc3 . t2
    mf2_k<us, us, us, 1><<<dim3(8, 1, 16), 256, 0, stream>>>(
        Wc2, 0, 256, cnOut + 512, (long)1024 * 1280, 1280, bc2, t2b, nullptr, 256, 128, 1024, 1);
    mf2_k<us, us, float, 1><<<dim3(8, 1, 16), 256, 0, stream>>>(
        Wc3, 0, 128, t2b, (long)1024 * 128, 128, bc3, fc_c, nullptr, 128, 32, 1024, 0);

    // 10: out32 = cov . fc_c; part2 = w_unc . out32
    mf2_k<float, float, float, 1><<<dim3(8, 1, 16), 256, 0, stream>>>(
        cov, 1024, 32, fc_c, (long)1024 * 32, 32, nullptr, out32, nullptr, 32, 32, 1024, 0);
    mf2_k<us, float, us, 1><<<dim3(8, 4, 16), 256, 0, stream>>>(
        Wunc, 0, 32, out32, (long)1024 * 32, 32, b_unc, part2b, nullptr, 32, 512, 1024, 0);

    // 11: p = cbrt(relu(part1*part2*part3))
    fuse_k<<<(unsigned)((NE + 255) / 256), 256, 0, stream>>>(
        cnOut, 1280, fc2t, part2b, part3b, pbuf, B, C, HW);

    // 12: out = w_out . p + b_out + content -> d_out fp32 [b][o][hw]
    mf2_k<us, us, float, 0><<<dim3(8, 4, 16), 256, 0, stream>>>(
        Wout, 0, 512, pbuf, TOK, 512, b_out, (float*)d_out, content, 512, 512, 1024, 0);
}

// Round 8
// 751.247 us; speedup vs baseline: 1.1112x; 1.0425x over previous
//
#include <hip/hip_runtime.h>
#include <hip/hip_bf16.h>
#include <hip/hip_fp16.h>
#include <math.h>

// Channel-major ([b][hw][c]) MFMA bf16 pipeline, fp32 accumulate.
// - g-branch: numerator sum(g^2) via bf16 MFMA; denominator analytic (sum_hw sn == 0).
// - conv3x3: weights fragment-major, direct global->VGPR; patch LDS double-buffered.
// - All MFMA GEMMs double-buffer LDS (1 barrier/K-step).
// - NEW: LDS-bounce epilogue for full-tile 2-byte outputs -> 256B-coalesced uint4
//   stores (old paths: 32B segments OUTT=0, 8B scatter OUTT=1/mfs).
// - Attention: fp16 logits (precision proven r5/r6) + one-pass softmax + bf16
//   part3 GEMM in r4 operand order (r7's swap = 8B-scatter regression).

typedef __attribute__((ext_vector_type(8))) short short8;
typedef __attribute__((ext_vector_type(4))) float f32x4;
typedef unsigned short us;
#define MFMA16 __builtin_amdgcn_mfma_f32_16x16x32_bf16

struct h16 { us v; };  // fp16 storage tag for GEMM output

template <class A, class B> struct SameT { static constexpr bool v = false; };
template <class A> struct SameT<A, A> { static constexpr bool v = true; };

__device__ inline float b2f(us b) { return __uint_as_float(((unsigned)b) << 16); }
__device__ inline us f2b(float f) {
    unsigned u = __float_as_uint(f);
    return (us)((u + 0x7FFFu + ((u >> 16) & 1u)) >> 16);
}

template <typename TOUT>
__device__ inline us cvt2b(float x) {
    if constexpr (SameT<TOUT, h16>::v) return __half_as_ushort(__float2half(x));
    else return f2b(x);
}

__device__ inline double blockReduceSumD(double v, double* sh) {
    int t = threadIdx.x;
    sh[t] = v; __syncthreads();
    for (int s = blockDim.x >> 1; s > 0; s >>= 1) {
        if (t < s) sh[t] += sh[t + s];
        __syncthreads();
    }
    double r = sh[0]; __syncthreads();
    return r;
}

// ---------- per-(b,c) spatial stats ----------
__global__ __launch_bounds__(256) void stats_k(const float* __restrict__ X,
                                               float* __restrict__ mean,
                                               float* __restrict__ inv, int HW) {
    __shared__ double sh[256];
    int bc = blockIdx.x;
    const float* x = X + (size_t)bc * HW;
    int t = threadIdx.x;
    float v[4];
    double s = 0.0;
    #pragma unroll
    for (int r = 0; r < 4; ++r) { v[r] = x[t + r * 256]; s += (double)v[r]; }
    double tot = blockReduceSumD(s, sh);
    double ss = 0.0;
    #pragma unroll
    for (int r = 0; r < 4; ++r) ss += (double)v[r] * (double)v[r];
    double tot2 = blockReduceSumD(ss, sh);
    if (t == 0) {
        double m = tot / HW;
        double var = (tot2 - tot * tot / HW) / (HW - 1);
        mean[bc] = (float)m;
        inv[bc] = (float)(1.0 / sqrt(var + 1e-5));
    }
}

// ---------- transpose [b][C][HW] fp32 -> up to 3 bf16 [b][HW][C] outputs ----------
__global__ __launch_bounds__(256) void trn_k(const float* __restrict__ X,
                                             const float* __restrict__ mean,
                                             const float* __restrict__ inv,
                                             us* __restrict__ Yn, us* __restrict__ Yc,
                                             us* __restrict__ Yr, int C, int HW) {
    __shared__ us Ln[64 * 65];
    __shared__ us Lc[64 * 65];
    __shared__ us Lr[64 * 65];
    int bz = blockIdx.z, c0 = blockIdx.y * 64, h0 = blockIdx.x * 64;
    const float* Xb = X + (size_t)bz * C * HW;
    int t = threadIdx.x;
    int cl = t >> 3, h8 = (t & 7) * 8;
    #pragma unroll
    for (int half = 0; half < 2; ++half) {
        int c = cl + half * 32;
        int gc = c0 + c;
        float m = mean[bz * C + gc], iv = inv[bz * C + gc];
        const float4* s4 = (const float4*)&Xb[(size_t)gc * HW + h0 + h8];
        float4 f0 = s4[0], f1 = s4[1];
        float vv[8] = {f0.x, f0.y, f0.z, f0.w, f1.x, f1.y, f1.z, f1.w};
        #pragma unroll
        for (int i = 0; i < 8; ++i) {
            int li = c * 65 + h8 + i;
            if (Yn) Ln[li] = f2b((vv[i] - m) * iv);
            if (Yc) Lc[li] = f2b(vv[i] - m);
            if (Yr) Lr[li] = f2b(vv[i]);
        }
    }
    __syncthreads();
    int hl = t >> 3, c8 = (t & 7) * 8;
    #pragma unroll
    for (int half = 0; half < 2; ++half) {
        int hh = hl + half * 32;
        size_t off = ((size_t)bz * HW + h0 + hh) * (size_t)C + c0 + c8;
        us tmp[8];
        if (Yn) {
            #pragma unroll
            for (int i = 0; i < 8; ++i) tmp[i] = Ln[(c8 + i) * 65 + hh];
            *(uint4*)&Yn[off] = *(const uint4*)tmp;
        }
        if (Yc) {
            #pragma unroll
            for (int i = 0; i < 8; ++i) tmp[i] = Lc[(c8 + i) * 65 + hh];
            *(uint4*)&Yc[off] = *(const uint4*)tmp;
        }
        if (Yr) {
            #pragma unroll
            for (int i = 0; i < 8; ++i) tmp[i] = Lr[(c8 + i) * 65 + hh];
            *(uint4*)&Yr[off] = *(const uint4*)tmp;
        }
    }
}

// ---------- staging: 16 k-contiguous elems -> bf16 LDS ----------
template <typename TE>
__device__ inline void stage16(const TE* __restrict__ src, bool valid, us* dst) {
    us tmp[16];
    if (valid) {
        if constexpr (sizeof(TE) == 2) {
            uint4 a = ((const uint4*)src)[0], b = ((const uint4*)src)[1];
            *(uint4*)&tmp[0] = a; *(uint4*)&tmp[8] = b;
        } else {
            const float4* s4 = (const float4*)src;
            float4 f0 = s4[0], f1 = s4[1], f2 = s4[2], f3 = s4[3];
            float vv[16] = {f0.x, f0.y, f0.z, f0.w, f1.x, f1.y, f1.z, f1.w,
                            f2.x, f2.y, f2.z, f2.w, f3.x, f3.y, f3.z, f3.w};
            #pragma unroll
            for (int i = 0; i < 16; ++i) tmp[i] = f2b(vv[i]);
        }
    } else {
        #pragma unroll
        for (int i = 0; i < 16; ++i) tmp[i] = 0;
    }
    ((uint4*)dst)[0] = *(uint4*)&tmp[0];
    ((uint4*)dst)[1] = *(uint4*)&tmp[8];
}

// ---------- 128x128 MFMA GEMM, double-buffered LDS, coalesced 2B epilogue ----------
// acc[m][n] = sum_k A[m][k] * B[n][k]
// OUTT=0: Y[b][m][n] row-major (+add_src fp32); OUTT=1: Y[b][n][m]
template <typename TAel, typename TBel, typename TOUT, int OUTT>
__global__ __launch_bounds__(256) void mf2_k(const TAel* __restrict__ A, long astride, int lda,
                                             const TBel* __restrict__ B, long bstride, int ldb,
                                             const float* __restrict__ bias,
                                             TOUT* __restrict__ Y,
                                             const float* __restrict__ add_src,
                                             int K, int M, int N, int relu) {
    __shared__ __align__(16) us smem[20480];  // 40KB: dbuf As/Bs; reused as out tile
    int bz = blockIdx.z;
    int mbase = blockIdx.y * 128, nbase = blockIdx.x * 128;
    const TAel* Ab = A + (size_t)bz * astride;
    const TBel* Bb = B + (size_t)bz * bstride;
    int t = threadIdx.x;
    int row = t & 127, kh = t >> 7;
    int wave = t >> 6, lane = t & 63, lm = lane & 15, q = lane >> 4;
    int mh = (wave >> 1) * 64, nh = (wave & 1) * 64;
    int gm = mbase + row, gn = nbase + row;
    bool vm = gm < M, vn = gn < N;

    auto As = [&](int buf) { return smem + buf * 5120; };
    auto Bs = [&](int buf) { return smem + 10240 + buf * 5120; };

    auto stage = [&](int buf, int kb) {
        stage16(Ab + (size_t)gm * lda + kb + kh * 16, vm, As(buf) + row * 40 + kh * 16);
        stage16(Bb + (size_t)gn * ldb + kb + kh * 16, vn, Bs(buf) + row * 40 + kh * 16);
    };

    f32x4 acc[4][4];
    #pragma unroll
    for (int i = 0; i < 4; ++i)
        #pragma unroll
        for (int j = 0; j < 4; ++j) acc[i][j] = (f32x4){0.f, 0.f, 0.f, 0.f};

    stage(0, 0);
    __syncthreads();
    int cur = 0;
    for (int kb = 0; kb < K; kb += 32) {
        if (kb + 32 < K) stage(cur ^ 1, kb + 32);
        short8 af[4], bf[4];
        #pragma unroll
        for (int i = 0; i < 4; ++i) af[i] = *(const short8*)(As(cur) + (mh + i * 16 + lm) * 40 + q * 8);
        #pragma unroll
        for (int j = 0; j < 4; ++j) bf[j] = *(const short8*)(Bs(cur) + (nh + j * 16 + lm) * 40 + q * 8);
        #pragma unroll
        for (int i = 0; i < 4; ++i)
            #pragma unroll
            for (int j = 0; j < 4; ++j)
                acc[i][j] = MFMA16(af[i], bf[j], acc[i][j], 0, 0, 0);
        __syncthreads();
        cur ^= 1;
    }

    // ---- fast path: full-tile 2-byte output via LDS bounce, coalesced uint4 ----
    if constexpr (sizeof(TOUT) == 2) {
        if (mbase + 128 <= M && nbase + 128 <= N) {
            us* Ts = smem;  // 128 x 136 (stride 136 us = 272 B, 16B-aligned rows)
            #pragma unroll
            for (int i = 0; i < 4; ++i) {
                int m0 = mh + i * 16 + q * 4;
                float bv[4];
                #pragma unroll
                for (int r = 0; r < 4; ++r) bv[r] = bias ? bias[mbase + m0 + r] : 0.f;
                #pragma unroll
                for (int j = 0; j < 4; ++j) {
                    int nl = nh + j * 16 + lm;
                    #pragma unroll
                    for (int r = 0; r < 4; ++r) {
                        float x = acc[i][j][r] + bv[r];
                        if (relu) x = (x > 0.f) ? x : 0.f;
                        us val = cvt2b<TOUT>(x);
                        if (OUTT == 0) Ts[(m0 + r) * 136 + nl] = val;
                        else Ts[nl * 136 + m0 + r] = val;
                    }
                }
            }
            __syncthreads();
            #pragma unroll
            for (int k2 = 0; k2 < 8; ++k2) {
                int flat = k2 * 256 + t;
                int r0 = flat >> 4, u = flat & 15;
                uint4 vv = *(const uint4*)&Ts[r0 * 136 + u * 8];
                us* dst;
                if (OUTT == 0)
                    dst = (us*)&Y[((size_t)bz * M + mbase + r0) * N + nbase + u * 8];
                else
                    dst = (us*)&Y[((size_t)bz * N + nbase + r0) * M + mbase + u * 8];
                *(uint4*)dst = vv;
            }
            return;
        }
    }

    #pragma unroll
    for (int i = 0; i < 4; ++i) {
        int m0 = mbase + mh + i * 16 + q * 4;
        if (m0 >= M) continue;
        float bv[4];
        #pragma unroll
        for (int r = 0; r < 4; ++r) bv[r] = bias ? bias[m0 + r] : 0.f;
        #pragma unroll
        for (int j = 0; j < 4; ++j) {
            int n = nbase + nh + j * 16 + lm;
            if (n >= N) continue;
            float v[4];
            #pragma unroll
            for (int r = 0; r < 4; ++r) {
                float x = acc[i][j][r] + bv[r];
                if (relu) x = (x > 0.f) ? x : 0.f;
                v[r] = x;
            }
            if (OUTT == 1) {
                size_t off = ((size_t)bz * N + n) * (size_t)M + m0;
                if constexpr (sizeof(TOUT) == 2) {
                    us o4[4];
                    #pragma unroll
                    for (int r = 0; r < 4; ++r) o4[r] = cvt2b<TOUT>(v[r]);
                    *(uint2*)&Y[off] = *(const uint2*)o4;
                } else {
                    float4 f4 = make_float4(v[0], v[1], v[2], v[3]);
                    *(float4*)&Y[off] = f4;
                }
            } else {
                #pragma unroll
                for (int r = 0; r < 4; ++r) {
                    size_t off = ((size_t)bz * M + m0 + r) * (size_t)N + n;
                    float x = v[r];
                    if (add_src) x += add_src[off];
                    if constexpr (sizeof(TOUT) == 2) {
                        us val = cvt2b<TOUT>(x);
                        *(us*)&Y[off] = val;
                    } else Y[off] = x;
                }
            }
        }
    }
}

// ---------- stacked-M MFMA GEMM (dbuf): A bf16 [Mstack][K], out [b][n][Mstack] ----------
struct SBias {
    const float* bp[10];
    int moff[10];
    unsigned relu;
};
__global__ __launch_bounds__(256) void mfs_k(const us* __restrict__ A,
                                             const us* __restrict__ B, long bstride, int ldb,
                                             us* __restrict__ Y, int ldy,
                                             SBias sb, int K, int N) {
    __shared__ __align__(16) us smem[20480];
    int bz = blockIdx.z;
    int mbase = blockIdx.y * 128, nbase = blockIdx.x * 128;
    const us* Bb = B + (size_t)bz * bstride;
    int t = threadIdx.x;
    int row = t & 127, kh = t >> 7;
    int wave = t >> 6, lane = t & 63, lm = lane & 15, q = lane >> 4;
    int mh = (wave >> 1) * 64, nh = (wave & 1) * 64;
    int relu = (sb.relu >> blockIdx.y) & 1;
    const float* bias = sb.bp[blockIdx.y];
    int moff = sb.moff[blockIdx.y];

    auto As = [&](int buf) { return smem + buf * 5120; };
    auto Bs = [&](int buf) { return smem + 10240 + buf * 5120; };

    auto stage = [&](int buf, int kb) {
        stage16(A + (size_t)(mbase + row) * K + kb + kh * 16, true, As(buf) + row * 40 + kh * 16);
        stage16(Bb + (size_t)(nbase + row) * ldb + kb + kh * 16, true, Bs(buf) + row * 40 + kh * 16);
    };

    f32x4 acc[4][4];
    #pragma unroll
    for (int i = 0; i < 4; ++i)
        #pragma unroll
        for (int j = 0; j < 4; ++j) acc[i][j] = (f32x4){0.f, 0.f, 0.f, 0.f};

    stage(0, 0);
    __syncthreads();
    int cur = 0;
    for (int kb = 0; kb < K; kb += 32) {
        if (kb + 32 < K) stage(cur ^ 1, kb + 32);
        short8 af[4], bf[4];
        #pragma unroll
        for (int i = 0; i < 4; ++i) af[i] = *(const short8*)(As(cur) + (mh + i * 16 + lm) * 40 + q * 8);
        #pragma unroll
        for (int j = 0; j < 4; ++j) bf[j] = *(const short8*)(Bs(cur) + (nh + j * 16 + lm) * 40 + q * 8);
        #pragma unroll
        for (int i = 0; i < 4; ++i)
            #pragma unroll
            for (int j = 0; j < 4; ++j)
                acc[i][j] = MFMA16(af[i], bf[j], acc[i][j], 0, 0, 0);
        __syncthreads();
        cur ^= 1;
    }

    // coalesced epilogue: Ts[n_local][m_local], rows are m-contiguous in Y
    us* Ts = smem;
    #pragma unroll
    for (int i = 0; i < 4; ++i) {
        int m0 = mh + i * 16 + q * 4;
        float bv[4];
        #pragma unroll
        for (int r = 0; r < 4; ++r) bv[r] = bias[mbase + m0 - moff + r];
        #pragma unroll
        for (int j = 0; j < 4; ++j) {
            int nl = nh + j * 16 + lm;
            #pragma unroll
            for (int r = 0; r < 4; ++r) {
                float x = acc[i][j][r] + bv[r];
                if (relu) x = (x > 0.f) ? x : 0.f;
                Ts[nl * 136 + m0 + r] = f2b(x);
            }
        }
    }
    __syncthreads();
    #pragma unroll
    for (int k2 = 0; k2 < 8; ++k2) {
        int flat = k2 * 256 + t;
        int r0 = flat >> 4, u = flat & 15;
        uint4 vv = *(const uint4*)&Ts[r0 * 136 + u * 8];
        *(uint4*)&Y[((size_t)bz * N + nbase + r0) * ldy + mbase + u * 8] = vv;
    }
}

// ---------- weight concat/convert fp32 -> bf16 arena ----------
struct CpyArg {
    const float* src[11];
    unsigned long long dstoff[11];
    int len[11];
};
__global__ __launch_bounds__(256) void wcat_k(CpyArg a, us* __restrict__ arena) {
    int seg = blockIdx.y;
    int idx = blockIdx.x * 256 + threadIdx.x;
    if (idx < a.len[seg]) arena[a.dstoff[seg] + idx] = f2b(a.src[seg][idx]);
}

// ---------- conv3x3 weight reorder: fragment-major ----------
__global__ __launch_bounds__(256) void reorder_wf_k(const float* __restrict__ W,
                                                    us* __restrict__ Wf, int O, int Cin) {
    int idx = blockIdx.x * 256 + threadIdx.x;
    int OT = O >> 6, KB = Cin >> 5;
    int total = OT * KB * 9 * 4 * 64;
    if (idx >= total) return;
    int lane = idx & 63;
    int f = idx >> 6;
    int i = f & 1, half = (f >> 1) & 1;
    int tf = f >> 2;
    int tap = tf % 9;
    int rest = tf / 9;
    int kb = rest % KB, ot = rest / KB;
    int o = ot * 64 + half * 32 + i * 16 + (lane & 15);
    int cb = kb * 32 + (lane >> 4) * 8;
    us v[8];
    #pragma unroll
    for (int e = 0; e < 8; ++e)
        v[e] = f2b(W[((size_t)o * Cin + cb + e) * 9 + tap]);
    *(uint4*)&Wf[(size_t)idx * 8] = *(const uint4*)v;
}

// ---------- patch staging for conv ----------
template <int PR>
__device__ inline void stage_patch(const us* __restrict__ Xb, us* __restrict__ dst,
                                   int pyb, int kb, int Cin, int IH, int IW, int t) {
    const int ITEMS = (2 * PR + 2) * 36 * 4;
    for (int i = t; i < ITEMS; i += 256) {
        int p = i >> 2, q8 = (i & 3) * 8;
        int r = p / 36, x = p - r * 36;
        int gy = pyb + r;
        uint4 v = make_uint4(0u, 0u, 0u, 0u);
        if (x < IW && gy < IH)
            v = *(const uint4*)&Xb[((size_t)(gy * IW + x)) * Cin + kb * 32 + q8];
        *(uint4*)&dst[p * 40 + q8] = v;
    }
}

// ---------- MFMA conv3x3 VALID, channel-major, dbuf patch, direct-global weights ----------
template <int PR>
__global__ __launch_bounds__(256) void conv_mf4_k(const us* __restrict__ X, long xbstride,
                                                  const us* __restrict__ Wf,
                                                  const float* __restrict__ bias,
                                                  us* __restrict__ Y, long ybstride,
                                                  int Cin, int O, int IH, int IW,
                                                  int OH, int OW) {
    __shared__ us patch[2][(2 * PR + 2) * 36 * 40];
    int bz = blockIdx.z;
    int obase = blockIdx.y * 64;
    int pyb = blockIdx.x * (2 * PR);
    const us* Xb = X + (size_t)bz * xbstride;
    int t = threadIdx.x;
    int wave = t >> 6, lane = t & 63, lm = lane & 15, q = lane >> 4;
    int half = wave >> 1, rw = wave & 1;
    int KB = Cin >> 5;
    const us* Wb = Wf + (size_t)(obase >> 6) * KB * 9 * 2048;

    f32x4 acc[PR][2][2];
    #pragma unroll
    for (int pr = 0; pr < PR; ++pr)
        #pragma unroll
        for (int i = 0; i < 2; ++i)
            #pragma unroll
            for (int j = 0; j < 2; ++j) acc[pr][i][j] = (f32x4){0.f, 0.f, 0.f, 0.f};

    stage_patch<PR>(Xb, patch[0], pyb, 0, Cin, IH, IW, t);
    __syncthreads();
    int cur = 0;
    for (int kb = 0; kb < KB; ++kb) {
        if (kb + 1 < KB) stage_patch<PR>(Xb, patch[cur ^ 1], pyb, kb + 1, Cin, IH, IW, t);
        const us* Wk = Wb + (size_t)kb * 9 * 2048;
        #pragma unroll
        for (int tap = 0; tap < 9; ++tap) {
            int ky = tap / 3, kx = tap - ky * 3;
            const us* wt = Wk + tap * 2048 + half * 1024;
            short8 a0 = *(const short8*)&wt[lane * 8];
            short8 a1 = *(const short8*)&wt[512 + lane * 8];
            #pragma unroll
            for (int pr = 0; pr < PR; ++pr) {
                int prow = (pr * 2 + rw + ky) * 36;
                short8 b0 = *(const short8*)&patch[cur][(prow + lm + kx) * 40 + q * 8];
                short8 b1 = *(const short8*)&patch[cur][(prow + 16 + lm + kx) * 40 + q * 8];
                acc[pr][0][0] = MFMA16(a0, b0, acc[pr][0][0], 0, 0, 0);
                acc[pr][0][1] = MFMA16(a0, b1, acc[pr][0][1], 0, 0, 0);
                acc[pr][1][0] = MFMA16(a1, b0, acc[pr][1][0], 0, 0, 0);
                acc[pr][1][1] = MFMA16(a1, b1, acc[pr][1][1], 0, 0, 0);
            }
        }
        __syncthreads();
        cur ^= 1;
    }

    us* Yb = Y + (size_t)bz * ybstride;
    #pragma unroll
    for (int pr = 0; pr < PR; ++pr) {
        int py = pyb + pr * 2 + rw;
        if (py >= OH) continue;
        #pragma unroll
        for (int i = 0; i < 2; ++i) {
            int m0 = obase + half * 32 + i * 16 + q * 4;
            #pragma unroll
            for (int j = 0; j < 2; ++j) {
                int px = j * 16 + lm;
                if (px >= OW) continue;
                us o4[4];
                #pragma unroll
                for (int r = 0; r < 4; ++r) {
                    float v = acc[pr][i][j][r] + bias[m0 + r];
                    v = (v > 0.f) ? v : 0.f;
                    o4[r] = f2b(v);
                }
                *(uint2*)&Yb[((size_t)(py * OW + px)) * O + m0] = *(const uint2*)o4;
            }
        }
    }
}

// ---------- legacy 32x32 fp32 GEMM (w_fc, N=16) ----------
__global__ __launch_bounds__(256) void gemm_k(const float* __restrict__ W,
                                              const float* __restrict__ X,
                                              const float* __restrict__ bias,
                                              float* __restrict__ Y,
                                              int C, int O, int N) {
    int obase = blockIdx.y * 32;
    __shared__ float As[32][33];
    __shared__ float Bs[32][33];
    int t = threadIdx.x;
    int tx = t & 15, ty = t >> 4;
    float acc00 = 0, acc01 = 0, acc10 = 0, acc11 = 0;
    for (int cb = 0; cb < C; cb += 32) {
        int k = t & 31, o0 = t >> 5;
        #pragma unroll
        for (int r = 0; r < 4; ++r) {
            int ol = o0 + r * 8;
            As[k][ol] = W[(size_t)(obase + ol) * C + cb + k];
        }
        int n0 = t & 31, k0 = t >> 5;
        #pragma unroll
        for (int r = 0; r < 4; ++r) {
            int k2 = k0 + r * 8;
            Bs[k2][n0] = (n0 < N) ? X[(size_t)(cb + k2) * N + n0] : 0.f;
        }
        __syncthreads();
        #pragma unroll
        for (int k2 = 0; k2 < 32; ++k2) {
            float a0 = As[k2][ty], a1 = As[k2][ty + 16];
            float b0 = Bs[k2][tx], b1 = Bs[k2][tx + 16];
            acc00 += a0 * b0; acc01 += a0 * b1;
            acc10 += a1 * b0; acc11 += a1 * b1;
        }
        __syncthreads();
    }
    float accs[2][2] = {{acc00, acc01}, {acc10, acc11}};
    #pragma unroll
    for (int i = 0; i < 2; ++i) {
        int o = obase + ty + i * 16;
        float bv = bias[o];
        #pragma unroll
        for (int j = 0; j < 2; ++j) {
            int n = tx + j * 16;
            if (n < N) Y[(size_t)o * N + n] = accs[i][j] + bv;
        }
    }
}

// ---------- FC_S two-stage: partial sums of g^2 then combine ----------
__global__ __launch_bounds__(256) void fcs3a_k(const us* __restrict__ g, int ldg,
                                               float* __restrict__ pa, int HW) {
    int b = blockIdx.x, j = blockIdx.y;  // grid (B, 8)
    int t = threadIdx.x;
    const us* gb = g + ((size_t)b * HW + (size_t)j * 128) * ldg + 2 * t;
    double s0 = 0.0, s1 = 0.0;
    #pragma unroll 4
    for (int hw = 0; hw < 128; ++hw) {
        unsigned u = *(const unsigned*)&gb[(size_t)hw * ldg];
        float f0 = b2f((us)(u & 0xFFFFu));
        float f1 = b2f((us)(u >> 16));
        s0 += (double)f0 * (double)f0;
        s1 += (double)f1 * (double)f1;
    }
    float2 w = make_float2((float)s0, (float)s1);
    *(float2*)&pa[((size_t)b * 8 + j) * 512 + 2 * t] = w;
}

__global__ __launch_bounds__(256) void fcs3b_k(const float* __restrict__ pa,
                                               const float* __restrict__ bg,
                                               float* __restrict__ fcs, int B, int HW) {
    int b = blockIdx.x;
    int t = threadIdx.x;
    double s0 = 0.0, s1 = 0.0;
    #pragma unroll
    for (int j = 0; j < 8; ++j) {
        float2 w = *(const float2*)&pa[((size_t)b * 8 + j) * 512 + 2 * t];
        s0 += (double)w.x; s1 += (double)w.y;
    }
    int c0 = 2 * t;
    fcs[(size_t)c0 * B + b] = (float)(s0 / ((double)HW * (double)bg[c0]));
    fcs[(size_t)(c0 + 1) * B + b] = (float)(s1 / ((double)HW * (double)bg[c0 + 1]));
}

// ---------- softmax fp16 logits -> bf16 P ----------
__global__ __launch_bounds__(256) void softmax_k(const us* __restrict__ S,
                                                 us* __restrict__ P) {
    __shared__ float sh[256];
    size_t row = blockIdx.x;
    const us* r = S + row * 1024;
    us* po = P + row * 1024;
    int t = threadIdx.x;
    us raw[4];
    *(uint2*)raw = *(const uint2*)&r[t * 4];
    float v[4];
    float m = -INFINITY;
    #pragma unroll
    for (int i = 0; i < 4; ++i) {
        v[i] = __half2float(__ushort_as_half(raw[i]));
        m = fmaxf(m, v[i]);
    }
    sh[t] = m; __syncthreads();
    for (int s = 128; s > 0; s >>= 1) { if (t < s) sh[t] = fmaxf(sh[t], sh[t + s]); __syncthreads(); }
    m = sh[0]; __syncthreads();
    float sum = 0;
    #pragma unroll
    for (int i = 0; i < 4; ++i) { v[i] = expf(v[i] - m); sum += v[i]; }
    sh[t] = sum; __syncthreads();
    for (int s = 128; s > 0; s >>= 1) { if (t < s) sh[t] += sh[t + s]; __syncthreads(); }
    float inv = 1.f / sh[0]; __syncthreads();
    #pragma unroll
    for (int i = 0; i < 4; ++i) raw[i] = f2b(v[i] * inv);
    *(uint2*)&po[t * 4] = *(const uint2*)raw;
}

// ---------- covariance from fs [b][784][32] fp32 ----------
__global__ __launch_bounds__(256) void cov2_k(const float* __restrict__ fs,
                                              float* __restrict__ cov, int Cd, int M) {
    __shared__ float Ls[196 * 36];
    int bb = blockIdx.x;
    int t = threadIdx.x;
    const float* p = fs + (size_t)bb * M * Cd;
    int c = t >> 3, d0 = (t & 7) * 4;
    float a0 = 0.f, a1 = 0.f, a2 = 0.f, a3 = 0.f;
    for (int ch = 0; ch < 4; ++ch) {
        __syncthreads();
        for (int i = t; i < 1568; i += 256) {
            int rowi = i >> 3, c4 = (i & 7) * 4;
            float4 v = *(const float4*)&p[(size_t)(ch * 196 + rowi) * Cd + c4];
            *(float4*)&Ls[rowi * 36 + c4] = v;
        }
        __syncthreads();
        for (int i = 0; i < 196; ++i) {
            float a = Ls[i * 36 + c];
            a0 += a * Ls[i * 36 + d0 + 0];
            a1 += a * Ls[i * 36 + d0 + 1];
            a2 += a * Ls[i * 36 + d0 + 2];
            a3 += a * Ls[i * 36 + d0 + 3];
        }
    }
    float invM = 1.f / (float)M;
    size_t base = ((size_t)bb * Cd + c) * Cd + d0;
    cov[base + 0] = a0 * invM;
    cov[base + 1] = a1 * invM;
    cov[base + 2] = a2 * invM;
    cov[base + 3] = a3 * invM;
}

// ---------- fused epilogue over [b][token][c]; ffc has row stride ldf ----------
__global__ __launch_bounds__(256) void fuse_k(const us* __restrict__ ffc, int ldf,
                                              const float* __restrict__ fc2t,
                                              const us* __restrict__ p2,
                                              const us* __restrict__ p3,
                                              us* __restrict__ out, int B, int C, int HW) {
    size_t idx = (size_t)blockIdx.x * 256 + threadIdx.x;
    size_t total = (size_t)B * C * HW;
    if (idx >= total) return;
    int c = (int)(idx & (size_t)(C - 1));
    size_t tok = idx >> 9;                  // b*HW + hw
    int b = (int)(idx / ((size_t)C * HW));
    float part1 = b2f(ffc[tok * ldf + c]) * fc2t[(size_t)c * B + b];
    float v = part1 * b2f(p2[idx]) * b2f(p3[idx]);
    v = (v > 0.f) ? v : 0.f;
    out[idx] = f2b(cbrtf(v));
}

// ---------- launch ----------
extern "C" void kernel_launch(void* const* d_in, const int* in_sizes, int n_in,
                              void* d_out, int out_size, void* d_ws, size_t ws_size,
                              hipStream_t stream) {
    typedef const float* fp;
    fp content = (fp)d_in[0];
    fp style   = (fp)d_in[1];
    fp wf_san = (fp)d_in[2],  bf_san = (fp)d_in[3];
    fp wg_san = (fp)d_in[4],  bg_san = (fp)d_in[5];
    fp wh_san = (fp)d_in[6],  bh_san = (fp)d_in[7];
    fp wf_mcc = (fp)d_in[8],  bf_mcc = (fp)d_in[9];
    fp wg_mcc = (fp)d_in[10], bg_mcc = (fp)d_in[11];
    fp w_fc   = (fp)d_in[12], b_fc   = (fp)d_in[13];
    fp w_out  = (fp)d_in[14], b_out  = (fp)d_in[15];
    fp wc1 = (fp)d_in[16], bc1 = (fp)d_in[17];
    fp wc2 = (fp)d_in[18], bc2 = (fp)d_in[19];
    fp wc3 = (fp)d_in[20], bc3 = (fp)d_in[21];
    fp ws1 = (fp)d_in[22], bs1 = (fp)d_in[23];
    fp ws2 = (fp)d_in[24], bs2 = (fp)d_in[25];
    fp ws3 = (fp)d_in[26], bs3 = (fp)d_in[27];
    fp w_unc = (fp)d_in[28], b_unc = (fp)d_in[29];

    const int B = 16, C = 512, HW = 1024;
    const size_t NE = (size_t)B * C * HW;       // 8388608
    const long TOK = (long)C * HW;              // 524288 per-batch elems
    const size_t MB = 1u << 20;
    char* base = (char*)d_ws;

    // ---- time-multiplexed layout ----
    us* cnT      = (us*)(base);                 //   0- 16  (trn -> cn-stack)
    us* snT      = (us*)(base + 16 * MB);       //  16- 32  (trn -> sn-stack)
    us* fs0T     = (us*)(base + 32 * MB);       //  32- 48  (trn -> conv1)
    us* s1       = (us*)(base + 48 * MB);       //  48- 56  (conv1 -> conv2)
    us* s2       = (us*)(base + 56 * MB);       //  56- 60  (conv2 -> ws3)
    float* fs_c  = (float*)(base + 60 * MB);    //  60- 62  (ws3 -> cov2)
    us* Sbuf16   = (us*)(base);                 //   0- 32  fp16 logits (cnT/snT dead)
    h16* Sh      = (h16*)(base);
    us* cnOut    = (us*)(base + 64 * MB);       //  64-104  [b][hw][1280]
    us* snOut    = (us*)(base + 104 * MB);      // 104-136  [b][hw][1024] (-> logits)
    us* part3b   = (us*)(base + 104 * MB);      // 104-120  (part3 -> fuse)
    us* part2b   = (us*)(base + 120 * MB);      // 120-136  (part2 -> fuse)
    us* Pb       = (us*)(base + 136 * MB);      // 136-168  (softmax -> part3)
    us* t2b      = (us*)(base + 136 * MB);      // 136-140  (after Pb dead)
    float* fc_c  = (float*)(base + 140 * MB);   // 140-142
    float* out32 = (float*)(base + 142 * MB);   // 142-144
    us* pbuf     = (us*)(base + 144 * MB);      // 144-160  (fuse -> out)
    us* styleT   = (us*)(base + 168 * MB);      // 168-184  (trn -> H)
    us* Hco      = (us*)(base + 184 * MB);      // 184-200  (H -> part3)

    char* misc = base + 200 * MB;
    us* Wr1   = (us*)(misc);                    // 2359296 B
    us* Wr2   = (us*)(misc + 2359296);          // 589824 B
    us* arena = (us*)(misc + 2949120);          // 3522560 B
    us* Wcn   = arena;                          // [1280][512]
    us* Wsn   = arena + 655360;                 // [1024][512]
    us* Wh    = arena + 1179648;                // [512][512]
    us* Wout  = arena + 1441792;                // [512][512]
    us* Wc2   = arena + 1703936;                // [128][256]
    us* Wc3   = arena + 1736704;                // [32][128]
    us* Ws3   = arena + 1740800;                // [32][128]
    us* Wunc  = arena + 1744896;                // [512][32]
    float* pa    = (float*)(misc + 6471680);    // 262144 B
    float* fcs   = (float*)(misc + 6733824);
    float* fc2t  = (float*)(misc + 6766592);
    float* cov   = (float*)(misc + 6799360);
    float* meanC = (float*)(misc + 6864896);
    float* invC  = (float*)(misc + 6897664);
    float* meanS = (float*)(misc + 6930432);
    float* invS  = (float*)(misc + 6963200);

    // 0: weight conversions
    CpyArg ca;
    const float* srcs[11] = {wf_mcc, wc1, wf_san, wg_mcc, wg_san, wh_san,
                             w_out, wc2, wc3, ws3, w_unc};
    int lens[11] = {262144, 131072, 262144, 262144, 262144, 262144,
                    262144, 32768, 4096, 4096, 16384};
    unsigned long long off = 0;
    for (int i = 0; i < 11; ++i) { ca.src[i] = srcs[i]; ca.dstoff[i] = off; ca.len[i] = lens[i]; off += lens[i]; }
    wcat_k<<<dim3(1024, 11), 256, 0, stream>>>(ca, arena);
    reorder_wf_k<<<576, 256, 0, stream>>>(ws1, Wr1, 256, 512);
    reorder_wf_k<<<72, 256, 0, stream>>>(ws2, Wr2, 128, 256);

    // 1: stats; bf16 transposes
    stats_k<<<B * C, 256, 0, stream>>>(content, meanC, invC, HW);
    stats_k<<<B * C, 256, 0, stream>>>(style, meanS, invS, HW);
    trn_k<<<dim3(16, 8, 16), 256, 0, stream>>>(content, meanC, invC, cnT, nullptr, nullptr, C, HW);
    trn_k<<<dim3(16, 8, 16), 256, 0, stream>>>(style, meanS, invS, snT, fs0T, styleT, C, HW);

    // 2: conv chain immediately (fs0T L3-hot)
    conv_mf4_k<1><<<dim3(15, 4, 16), 256, 0, stream>>>(fs0T, TOK, Wr1, bs1,
                                                       s1, (long)900 * 256, 512, 256, 32, 32, 30, 30);
    conv_mf4_k<1><<<dim3(14, 2, 16), 256, 0, stream>>>(s1, (long)900 * 256, Wr2, bs2,
                                                       s2, (long)784 * 128, 256, 128, 30, 30, 28, 28);
    mf2_k<us, us, float, 1><<<dim3(7, 1, 16), 256, 0, stream>>>(
        Ws3, 0, 128, s2, (long)784 * 128, 128, bs3, fs_c, nullptr, 128, 32, 784, 0);
    cov2_k<<<B, 256, 0, stream>>>(fs_c, cov, 32, 784);

    // 3: cn-stack GEMM -> cnOut [b][hw][{ffc:0-511, t1:512-767(relu), F:768-1279}]
    {
        SBias sb;
        for (int y = 0; y < 4; ++y) { sb.bp[y] = bf_mcc; sb.moff[y] = 0; }
        for (int y = 4; y < 6; ++y) { sb.bp[y] = bc1; sb.moff[y] = 512; }
        for (int y = 6; y < 10; ++y) { sb.bp[y] = bf_san; sb.moff[y] = 768; }
        sb.relu = 0x030u;  // t1 blocks only
        mfs_k<<<dim3(8, 10, 16), 256, 0, stream>>>(Wcn, cnT, TOK, 512, cnOut, 1280, sb, 512, 1024);
    }

    // 4: sn-stack GEMM -> snOut [b][hw][{g:0-511, G:512-1023}]
    {
        SBias sb;
        for (int y = 0; y < 4; ++y) { sb.bp[y] = bg_mcc; sb.moff[y] = 0; }
        for (int y = 4; y < 8; ++y) { sb.bp[y] = bg_san; sb.moff[y] = 512; }
        for (int y = 8; y < 10; ++y) { sb.bp[y] = bg_mcc; sb.moff[y] = 0; }
        sb.relu = 0u;
        mfs_k<<<dim3(8, 8, 16), 256, 0, stream>>>(Wsn, snT, TOK, 512, snOut, 1024, sb, 512, 1024);
    }

    // 5: FC_S (analytic denominator) two-stage; fc2t
    fcs3a_k<<<dim3(B, 8), 256, 0, stream>>>(snOut, 1024, pa, HW);
    fcs3b_k<<<B, 256, 0, stream>>>(pa, bg_mcc, fcs, B, HW);
    gemm_k<<<dim3(1, 16, 1), 256, 0, stream>>>(w_fc, fcs, b_fc, fc2t, 512, 512, 16);

    // 6: H = wh_san . style (styleT L3-warm; independent of logits)
    mf2_k<us, us, us, 0><<<dim3(8, 4, 16), 256, 0, stream>>>(
        Wh, 0, 512, styleT, TOK, 512, bh_san, Hco, nullptr, 512, 512, 1024, 0);

    // 7: logits S[i][j] = F . G -> fp16, coalesced epilogue; softmax -> Pb
    mf2_k<us, us, h16, 0><<<dim3(8, 8, 16), 256, 0, stream>>>(
        cnOut + 768, (long)1024 * 1280, 1280, snOut + 512, (long)1024 * 1024, 1024,
        nullptr, Sh, nullptr, 512, 1024, 1024, 0);
    softmax_k<<<B * HW, 256, 0, stream>>>(Sbuf16, Pb);

    // 8: part3[b][i][c] = sum_j P[i][j] H[c][j]  (r4 operand order, coalesced epi)
    mf2_k<us, us, us, 0><<<dim3(4, 8, 16), 256, 0, stream>>>(
        Pb, (long)1024 * 1024, 1024, Hco, TOK, 1024, nullptr, part3b, nullptr,
        1024, 1024, 512, 0);

    // 9: fc chain tail: t2 = relu(wc2 . t1); fc_c = wc3 . t2
    mf2_k<us, us, us, 1><<<dim3(8, 1, 16), 256, 0, stream>>>(
        Wc2, 0, 256, cnOut + 512, (long)1024 * 1280, 1280, bc2, t2b, nullptr, 256, 128, 1024, 1);
    mf2_k<us, us, float, 1><<<dim3(8, 1, 16), 256, 0, stream>>>(
        Wc3, 0, 128, t2b, (long)1024 * 128, 128, bc3, fc_c, nullptr, 128, 32, 1024, 0);

    // 10: out32 = cov . fc_c; part2 = w_unc . out32
    mf2_k<float, float, float, 1><<<dim3(8, 1, 16), 256, 0, stream>>>(
        cov, 1024, 32, fc_c, (long)1024 * 32, 32, nullptr, out32, nullptr, 32, 32, 1024, 0);
    mf2_k<us, float, us, 1><<<dim3(8, 4, 16), 256, 0, stream>>>(
        Wunc, 0, 32, out32, (long)1024 * 32, 32, b_unc, part2b, nullptr, 32, 512, 1024, 0);

    // 11: p = cbrt(relu(part1*part2*part3))
    fuse_k<<<(unsigned)((NE + 255) / 256), 256, 0, stream>>>(
        cnOut, 1280, fc2t, part2b, part3b, pbuf, B, C, HW);

    // 12: out = w_out . p + b_out + content -> d_out fp32 [b][o][hw]
    mf2_k<us, us, float, 0><<<dim3(8, 4, 16), 256, 0, stream>>>(
        Wout, 0, 512, pbuf, TOK, 512, b_out, (float*)d_out, content, 512, 512, 1024, 0);
}